// Round 1
// 540.762 us; speedup vs baseline: 1.0936x; 1.0936x over previous
//
#include <hip/hip_runtime.h>

typedef __bf16 bf16;
typedef __bf16 bf16x8 __attribute__((ext_vector_type(8)));
typedef __bf16 bf16x4 __attribute__((ext_vector_type(4)));
typedef float f32x4 __attribute__((ext_vector_type(4)));

#define B_ 4
#define N_ 2048
#define C_ 1024
#define H_ 16
#define HKV_ 4
#define D_ 64

// fold: 1.5 (qk_gain) * 0.125 (1/sqrt(64)) * log2(e)  -> use exp2f in softmax
#define QSCALE 0.2705053201666806f
#define NEGINF (-1.0e30f)

// ---------------------------------------------------------------------------
// GEMM: C[M][.] = A[M][K] * B[K][.].
//   A: row-major, dtype AT (float -> converted to bf16 during LDS staging,
//      bf16 -> copied directly).
//   B: row-major FP32 with row stride bn_stride; transposed AND converted to
//      bf16 during LDS staging into Bs[n][k].
//   C: dtype OT (bf16 intermediates, float final), at [row*ostride+col0+col].
// 128x128 tile, BK=64, 4 waves x (64x64 quadrant) via 4x4 16x16x32 MFMAs.
template <typename AT, typename OT>
__global__ __launch_bounds__(256) void gemm_any(const AT* __restrict__ A,
                                                const float* __restrict__ B,
                                                OT* __restrict__ Cmat,
                                                int M, int K, int bn_stride,
                                                int ostride, int col0) {
  __shared__ __align__(16) bf16 As[128 * 72];
  __shared__ __align__(16) bf16 Bs[128 * 72];
  int m0 = blockIdx.x * 128, n0 = blockIdx.y * 128;
  int tid = threadIdx.x;
  int wave = tid >> 6, lane = tid & 63;
  int quad = lane >> 4, lr = lane & 15;
  int wr = (wave >> 1) * 64, wc = (wave & 1) * 64;

  f32x4 acc[4][4];
  const f32x4 z = {0.f, 0.f, 0.f, 0.f};
#pragma unroll
  for (int i = 0; i < 4; ++i)
#pragma unroll
    for (int j = 0; j < 4; ++j) acc[i][j] = z;

  for (int k0 = 0; k0 < K; k0 += 64) {
    __syncthreads();
    if constexpr (sizeof(AT) == 4) {
#pragma unroll
      for (int i = 0; i < 8; ++i) {
        int c = tid + i * 256;
        int row = c >> 4, off4 = (c & 15) * 4;
        f32x4 av = *(const f32x4*)(A + (size_t)(m0 + row) * K + k0 + off4);
        bf16x4 a16;
#pragma unroll
        for (int j = 0; j < 4; ++j) a16[j] = (bf16)av[j];
        *(bf16x4*)(As + row * 72 + off4) = a16;
      }
    } else {
#pragma unroll
      for (int i = 0; i < 4; ++i) {
        int c = tid + i * 256;
        int row = c >> 3, off = (c & 7) * 8;
        *(bf16x8*)(As + row * 72 + off) =
            *(const bf16x8*)(A + (size_t)(m0 + row) * K + k0 + off);
      }
    }
#pragma unroll
    for (int i = 0; i < 8; ++i) {
      int c = tid + i * 256;
      int k = c >> 5, n4 = (c & 31) * 4;
      f32x4 bv = *(const f32x4*)(B + (size_t)(k0 + k) * bn_stride + n0 + n4);
#pragma unroll
      for (int j = 0; j < 4; ++j) Bs[(n4 + j) * 72 + k] = (bf16)bv[j];
    }
    __syncthreads();
#pragma unroll
    for (int kx = 0; kx < 2; ++kx) {
      bf16x8 af[4], bfr[4];
#pragma unroll
      for (int t = 0; t < 4; ++t) {
        af[t] = *(const bf16x8*)(As + (wr + t * 16 + lr) * 72 + kx * 32 + quad * 8);
        bfr[t] = *(const bf16x8*)(Bs + (wc + t * 16 + lr) * 72 + kx * 32 + quad * 8);
      }
#pragma unroll
      for (int rt = 0; rt < 4; ++rt)
#pragma unroll
        for (int ct = 0; ct < 4; ++ct)
          acc[rt][ct] = __builtin_amdgcn_mfma_f32_16x16x32_bf16(af[rt], bfr[ct],
                                                                acc[rt][ct], 0, 0, 0);
    }
  }
#pragma unroll
  for (int rt = 0; rt < 4; ++rt)
#pragma unroll
    for (int ct = 0; ct < 4; ++ct)
#pragma unroll
      for (int r = 0; r < 4; ++r) {
        int row = m0 + wr + rt * 16 + quad * 4 + r;
        int col = col0 + n0 + wc + ct * 16 + lr;
        Cmat[(size_t)row * ostride + col] = (OT)acc[rt][ct][r];
      }
}

// ---------------------------------------------------------------------------
// V transpose: kv [B*N][512] (v = cols 256..511, head hkv at 256+hkv*64)
//           -> vt [B][HKV][D][N]
__global__ __launch_bounds__(256) void transpose_v(const bf16* __restrict__ kv,
                                                   bf16* __restrict__ vt) {
  __shared__ __align__(16) bf16 lds[64 * 72];
  int nt = blockIdx.x;
  int bh = blockIdx.y;
  int b = bh >> 2, hkv = bh & 3;
  int tid = threadIdx.x;
#pragma unroll
  for (int i = 0; i < 2; ++i) {
    int c = tid + i * 256;
    int tok = c >> 3, off = (c & 7) * 8;
    *(bf16x8*)(lds + tok * 72 + off) =
        *(const bf16x8*)(kv + (size_t)(b * N_ + nt * 64 + tok) * 512 + 256 + hkv * 64 + off);
  }
  __syncthreads();
#pragma unroll
  for (int i = 0; i < 2; ++i) {
    int c = tid + i * 256;
    int d = c >> 3, toff = (c & 7) * 8;
    bf16x8 tv;
#pragma unroll
    for (int j = 0; j < 8; ++j) tv[j] = lds[(toff + j) * 72 + d];
    *(bf16x8*)(vt + ((size_t)bh * 64 + d) * N_ + nt * 64 + toff) = tv;
  }
}

// ---------------------------------------------------------------------------
// Per-head RMSNorm + RoPE, in place (bf16 data, fp32 math). One wave per
// (token, head) 64-vector. q heads get folded QSCALE; k heads don't.
__global__ __launch_bounds__(256) void norm_rope(bf16* __restrict__ q,
                                                 bf16* __restrict__ kv) {
  int wave = threadIdx.x >> 6, lane = threadIdx.x & 63;
  int hid = blockIdx.x * 4 + wave;
  int t = hid / 20;
  int sub = hid - t * 20;
  int n = t & (N_ - 1);
  bf16* ptr;
  float oscale;
  if (sub < 16) {
    ptr = q + ((size_t)t * 16 + sub) * 64;
    oscale = QSCALE;
  } else {
    ptr = kv + (size_t)t * 512 + (sub - 16) * 64;
    oscale = 1.0f;
  }
  float x = (float)ptr[lane];
  float ss = x * x;
  ss += __shfl_xor(ss, 1);
  ss += __shfl_xor(ss, 2);
  ss += __shfl_xor(ss, 4);
  ss += __shfl_xor(ss, 8);
  ss += __shfl_xor(ss, 16);
  ss += __shfl_xor(ss, 32);
  float rn = rsqrtf(ss * (1.0f / 64.0f) + 1.1920929e-07f);
  float xn = x * rn;
  float pr = __shfl_xor(xn, 32);
  float rot = (lane < 32) ? -pr : pr;
  float ang = (float)n * exp2f(-0.41524101186092029f * (float)(lane & 31));
  float sv, cv;
  sincosf(ang, &sv, &cv);
  ptr[lane] = (bf16)((xn * cv + rot * sv) * oscale);
}

// ---------------------------------------------------------------------------
// Causal flash attention with GQA — TRANSPOSED dataflow (S^T / O^T).
//   S^T = K·Q^T   (A = K from Ks[key][d],  B = Q^T via q[qrow][d] loads)
//   O^T = V^T·P^T (A = V^T from Vs[d][key], B = P^T via Ps[qrow][key] loads)
// Round-0 change set:
//   1. Complement-balanced block->(qt,h,b) mapping: co-resident blocks
//      {id, id+256, id+512, id+768} (round-robin dispatch over 256 CUs) get
//      qt = {x, 15-x, (x+8)&15, (7-x)&15}; per-CU work = 68 k-tile units for
//      EVERY CU (was 8..128 -> 16x skew, the cause of 12% occupancy).
//   2. Async reg-staging (T14): next tile's K/V global loads are issued
//      before computing the current tile; LDS writes happen after a raw
//      s_barrier (NOT __syncthreads, which drains vmcnt and would serialize).
//   3. s_setprio(1) around MFMA clusters (T5).
__global__ __launch_bounds__(256, 4) void attn(bf16* __restrict__ q,
                                               const bf16* __restrict__ kv,
                                               const bf16* __restrict__ vt) {
  __shared__ __align__(16) bf16 Ks[64 * 72];   // [key][d]
  __shared__ __align__(16) bf16 Vs[64 * 72];   // [d][key]
  __shared__ __align__(16) bf16 Ps[128 * 72];  // [q-row][key], wave-private rows
  int id = blockIdx.x;
  int round = id >> 8, rr = id & 255;
  int xq = rr & 15, h = rr >> 4, b = round;
  int qt = (round == 0) ? xq
         : (round == 1) ? (15 - xq)
         : (round == 2) ? ((xq + 8) & 15)
                        : ((7 - xq) & 15);
  int hkv = h >> 2;
  int tid = threadIdx.x;
  int wave = tid >> 6, lane = tid & 63;
  int quad = lane >> 4, lr = lane & 15;
  int qrow0 = qt * 128 + wave * 32;

  // staging geometry: thread covers rows srow and srow+32 at column soff
  int srow = tid >> 3, soff = (tid & 7) * 8;

  // Q fragments (serve as B-operand = Q^T): lane holds Q[qrow0+rt*16+lr][kx*32+quad*8..]
  bf16x8 qf[2][2];
#pragma unroll
  for (int rt = 0; rt < 2; ++rt)
#pragma unroll
    for (int kx = 0; kx < 2; ++kx)
      qf[rt][kx] = *(const bf16x8*)(
          q + ((size_t)(b * N_ + qrow0 + rt * 16 + lr) * H_ + h) * D_ + kx * 32 + quad * 8);

  f32x4 acc[2][4];  // acc[rt][dt] = O^T tile: row d=dt*16+quad*4+r, col qrow=rt*16+lr
  const f32x4 z = {0.f, 0.f, 0.f, 0.f};
  float m_i[2], l_i[2];  // per-lane scalars (q-row = qrow0 + rt*16 + lr)
#pragma unroll
  for (int rt = 0; rt < 2; ++rt) {
#pragma unroll
    for (int dt = 0; dt < 4; ++dt) acc[rt][dt] = z;
    m_i[rt] = NEGINF;
    l_i[rt] = 0.f;
  }

  int nkt = qt * 2 + 2;

  // ---- prologue: stage tile 0 synchronously
  bf16x8 sk0, sk1, sv0, sv1;
  {
    sk0 = *(const bf16x8*)(kv + (size_t)(b * N_ + srow) * 512 + hkv * 64 + soff);
    sk1 = *(const bf16x8*)(kv + (size_t)(b * N_ + srow + 32) * 512 + hkv * 64 + soff);
    sv0 = *(const bf16x8*)(vt + ((size_t)(b * HKV_ + hkv) * 64 + srow) * N_ + soff);
    sv1 = *(const bf16x8*)(vt + ((size_t)(b * HKV_ + hkv) * 64 + srow + 32) * N_ + soff);
    *(bf16x8*)(Ks + srow * 72 + soff) = sk0;
    *(bf16x8*)(Ks + (srow + 32) * 72 + soff) = sk1;
    *(bf16x8*)(Vs + srow * 72 + soff) = sv0;
    *(bf16x8*)(Vs + (srow + 32) * 72 + soff) = sv1;
  }
  asm volatile("s_waitcnt lgkmcnt(0)" ::: "memory");
  __builtin_amdgcn_s_barrier();
  __builtin_amdgcn_sched_barrier(0);

  for (int kt = 0; kt < nkt; ++kt) {
    // ---- issue NEXT tile's global loads early (in flight across compute)
    bool pf = (kt + 1 < nkt);
    if (pf) {
      int krow = (kt + 1) * 64;
      sk0 = *(const bf16x8*)(kv + (size_t)(b * N_ + krow + srow) * 512 + hkv * 64 + soff);
      sk1 = *(const bf16x8*)(kv + (size_t)(b * N_ + krow + srow + 32) * 512 + hkv * 64 + soff);
      sv0 = *(const bf16x8*)(vt + ((size_t)(b * HKV_ + hkv) * 64 + srow) * N_ + krow + soff);
      sv1 = *(const bf16x8*)(vt + ((size_t)(b * HKV_ + hkv) * 64 + srow + 32) * N_ + krow + soff);
    }

    if (kt * 64 <= qrow0 + 31) {
      // S^T = K·Q^T: st[rt][ct] — key = kt*64 + ct*16 + quad*4 + r, qrow col = lr
      f32x4 st[2][4];
#pragma unroll
      for (int rt = 0; rt < 2; ++rt)
#pragma unroll
        for (int ct = 0; ct < 4; ++ct) st[rt][ct] = z;
#pragma unroll
      for (int kx = 0; kx < 2; ++kx) {
        bf16x8 kf[4];
#pragma unroll
        for (int ct = 0; ct < 4; ++ct)
          kf[ct] = *(const bf16x8*)(Ks + (ct * 16 + lr) * 72 + kx * 32 + quad * 8);
        __builtin_amdgcn_s_setprio(1);
#pragma unroll
        for (int rt = 0; rt < 2; ++rt)
#pragma unroll
          for (int ct = 0; ct < 4; ++ct)
            st[rt][ct] = __builtin_amdgcn_mfma_f32_16x16x32_bf16(kf[ct], qf[rt][kx],
                                                                 st[rt][ct], 0, 0, 0);
        __builtin_amdgcn_s_setprio(0);
      }
      // Causal mask (diagonal-crossing tiles only): mask key > qrow
      if (kt * 64 + 63 > qrow0) {
#pragma unroll
        for (int rt = 0; rt < 2; ++rt) {
          int qrow = qrow0 + rt * 16 + lr;
#pragma unroll
          for (int ct = 0; ct < 4; ++ct)
#pragma unroll
            for (int r = 0; r < 4; ++r) {
              int key = kt * 64 + ct * 16 + quad * 4 + r;
              if (key > qrow) st[rt][ct][r] = NEGINF;
            }
        }
      }
      // Online softmax: per-lane scalar state, 2+2 shuffles total per rt
#pragma unroll
      for (int rt = 0; rt < 2; ++rt) {
        float mx = NEGINF;
#pragma unroll
        for (int ct = 0; ct < 4; ++ct)
#pragma unroll
          for (int r = 0; r < 4; ++r) mx = fmaxf(mx, st[rt][ct][r]);
        mx = fmaxf(mx, __shfl_xor(mx, 16));
        mx = fmaxf(mx, __shfl_xor(mx, 32));
        float mnew = fmaxf(m_i[rt], mx);
        float alpha = exp2f(m_i[rt] - mnew);
        m_i[rt] = mnew;
        float rs = 0.f;
#pragma unroll
        for (int ct = 0; ct < 4; ++ct)
#pragma unroll
          for (int r = 0; r < 4; ++r) {
            float p = exp2f(st[rt][ct][r] - mnew);
            st[rt][ct][r] = p;
            rs += p;
          }
        rs += __shfl_xor(rs, 16);
        rs += __shfl_xor(rs, 32);
        l_i[rt] = l_i[rt] * alpha + rs;
#pragma unroll
        for (int dt = 0; dt < 4; ++dt)
#pragma unroll
          for (int r = 0; r < 4; ++r) acc[rt][dt][r] *= alpha;
        // P^T -> Ps[qrow][key]: b64 vector writes (keys quad*4+r contiguous)
#pragma unroll
        for (int ct = 0; ct < 4; ++ct) {
          bf16x4 pk;
#pragma unroll
          for (int r = 0; r < 4; ++r) pk[r] = (bf16)st[rt][ct][r];
          *(bf16x4*)(Ps + (wave * 32 + rt * 16 + lr) * 72 + ct * 16 + quad * 4) = pk;
        }
      }
      // Wave-local LDS ordering (rows wave-private, guard wave-uniform)
      asm volatile("s_waitcnt lgkmcnt(0)" ::: "memory");
      // O^T += V^T·P^T
#pragma unroll
      for (int kx = 0; kx < 2; ++kx) {
        bf16x8 vf[4], pfr[2];
#pragma unroll
        for (int dt = 0; dt < 4; ++dt)
          vf[dt] = *(const bf16x8*)(Vs + (dt * 16 + lr) * 72 + kx * 32 + quad * 8);
#pragma unroll
        for (int rt = 0; rt < 2; ++rt)
          pfr[rt] = *(const bf16x8*)(Ps + (wave * 32 + rt * 16 + lr) * 72 + kx * 32 + quad * 8);
        __builtin_amdgcn_s_setprio(1);
#pragma unroll
        for (int rt = 0; rt < 2; ++rt)
#pragma unroll
          for (int dt = 0; dt < 4; ++dt)
            acc[rt][dt] = __builtin_amdgcn_mfma_f32_16x16x32_bf16(vf[dt], pfr[rt],
                                                                  acc[rt][dt], 0, 0, 0);
        __builtin_amdgcn_s_setprio(0);
      }
    }

    // ---- all waves done READING tile kt (LDS reads already consumed; no
    // vmcnt drain here — prefetch loads stay in flight across the barrier)
    __builtin_amdgcn_s_barrier();
    __builtin_amdgcn_sched_barrier(0);
    if (pf) {
      // compiler inserts s_waitcnt vmcnt(0) before first use of sk*/sv*
      *(bf16x8*)(Ks + srow * 72 + soff) = sk0;
      *(bf16x8*)(Ks + (srow + 32) * 72 + soff) = sk1;
      *(bf16x8*)(Vs + srow * 72 + soff) = sv0;
      *(bf16x8*)(Vs + (srow + 32) * 72 + soff) = sv1;
      asm volatile("s_waitcnt lgkmcnt(0)" ::: "memory");
    }
    __builtin_amdgcn_s_barrier();  // tile kt+1 visible to all waves
    __builtin_amdgcn_sched_barrier(0);
  }

  // Epilogue: y = O / l — O^T layout => lane owns q-row (rt, lr), d = dt*16+quad*4+r
#pragma unroll
  for (int rt = 0; rt < 2; ++rt) {
    float inv = 1.0f / l_i[rt];
    int qrow = qrow0 + rt * 16 + lr;
#pragma unroll
    for (int dt = 0; dt < 4; ++dt) {
      bf16x4 ov;
#pragma unroll
      for (int r = 0; r < 4; ++r) ov[r] = (bf16)(acc[rt][dt][r] * inv);
      *(bf16x4*)(q + ((size_t)(b * N_ + qrow) * H_ + h) * D_ + dt * 16 + quad * 4) = ov;
    }
  }
}

// ---------------------------------------------------------------------------
extern "C" void kernel_launch(void* const* d_in, const int* in_sizes, int n_in,
                              void* d_out, int out_size, void* d_ws, size_t ws_size,
                              hipStream_t stream) {
  // Inputs FP32; output FP32 (verified round 9). Intermediates bf16.
  const float* x = (const float*)d_in[0];
  const float* wq = (const float*)d_in[1];
  const float* wk = (const float*)d_in[2];
  const float* wv = (const float*)d_in[3];
  const float* wo = (const float*)d_in[4];
  float* out = (float*)d_out;
  char* ws = (char*)d_ws;
  // ws (28 MB): q/y 16 MB [0,16M) | kv 8 MB [16M,24M) | vt 4 MB [24M,28M)
  bf16* q = (bf16*)(ws);
  bf16* kv = (bf16*)(ws + 16777216);
  bf16* vt = (bf16*)(ws + 25165824);

  gemm_any<float, bf16><<<dim3(64, 8), 256, 0, stream>>>(x, wq, q, 8192, 1024, 1024, 1024, 0);
  gemm_any<float, bf16><<<dim3(64, 2), 256, 0, stream>>>(x, wk, kv, 8192, 1024, 256, 512, 0);
  gemm_any<float, bf16><<<dim3(64, 2), 256, 0, stream>>>(x, wv, kv, 8192, 1024, 256, 512, 256);
  norm_rope<<<dim3(40960), 256, 0, stream>>>(q, kv);
  transpose_v<<<dim3(32, 16), 256, 0, stream>>>(kv, vt);
  attn<<<dim3(1024), 256, 0, stream>>>(q, kv, vt);
  gemm_any<bf16, float><<<dim3(64, 8), 256, 0, stream>>>(q, wo, out, 8192, 1024, 1024, 1024, 0);
}

// Round 2
// 512.615 us; speedup vs baseline: 1.1537x; 1.0549x over previous
//
#include <hip/hip_runtime.h>

typedef __bf16 bf16;
typedef __bf16 bf16x8 __attribute__((ext_vector_type(8)));
typedef __bf16 bf16x4 __attribute__((ext_vector_type(4)));
typedef float f32x4 __attribute__((ext_vector_type(4)));

#define B_ 4
#define N_ 2048
#define C_ 1024
#define H_ 16
#define HKV_ 4
#define D_ 64

// fold: 1.5 (qk_gain) * 0.125 (1/sqrt(64)) * log2(e)  -> use exp2f in softmax
#define QSCALE 0.2705053201666806f
#define NEGINF (-1.0e30f)

// ---------------------------------------------------------------------------
// GEMM: C[M][.] = A[M][K] * B[K][.].
//   A: row-major, dtype AT (float -> converted to bf16 during LDS staging,
//      bf16 -> copied directly).
//   B: row-major FP32 with row stride bn_stride; transposed AND converted to
//      bf16 during LDS staging into Bs[n][k].
//   C: dtype OT (bf16 intermediates, float final), at [row*ostride+col0+col].
// 128x128 tile, BK=64, 4 waves x (64x64 quadrant) via 4x4 16x16x32 MFMAs.
template <typename AT, typename OT>
__global__ __launch_bounds__(256) void gemm_any(const AT* __restrict__ A,
                                                const float* __restrict__ B,
                                                OT* __restrict__ Cmat,
                                                int M, int K, int bn_stride,
                                                int ostride, int col0) {
  __shared__ __align__(16) bf16 As[128 * 72];
  __shared__ __align__(16) bf16 Bs[128 * 72];
  int m0 = blockIdx.x * 128, n0 = blockIdx.y * 128;
  int tid = threadIdx.x;
  int wave = tid >> 6, lane = tid & 63;
  int quad = lane >> 4, lr = lane & 15;
  int wr = (wave >> 1) * 64, wc = (wave & 1) * 64;

  f32x4 acc[4][4];
  const f32x4 z = {0.f, 0.f, 0.f, 0.f};
#pragma unroll
  for (int i = 0; i < 4; ++i)
#pragma unroll
    for (int j = 0; j < 4; ++j) acc[i][j] = z;

  for (int k0 = 0; k0 < K; k0 += 64) {
    __syncthreads();
    if constexpr (sizeof(AT) == 4) {
#pragma unroll
      for (int i = 0; i < 8; ++i) {
        int c = tid + i * 256;
        int row = c >> 4, off4 = (c & 15) * 4;
        f32x4 av = *(const f32x4*)(A + (size_t)(m0 + row) * K + k0 + off4);
        bf16x4 a16;
#pragma unroll
        for (int j = 0; j < 4; ++j) a16[j] = (bf16)av[j];
        *(bf16x4*)(As + row * 72 + off4) = a16;
      }
    } else {
#pragma unroll
      for (int i = 0; i < 4; ++i) {
        int c = tid + i * 256;
        int row = c >> 3, off = (c & 7) * 8;
        *(bf16x8*)(As + row * 72 + off) =
            *(const bf16x8*)(A + (size_t)(m0 + row) * K + k0 + off);
      }
    }
#pragma unroll
    for (int i = 0; i < 8; ++i) {
      int c = tid + i * 256;
      int k = c >> 5, n4 = (c & 31) * 4;
      f32x4 bv = *(const f32x4*)(B + (size_t)(k0 + k) * bn_stride + n0 + n4);
#pragma unroll
      for (int j = 0; j < 4; ++j) Bs[(n4 + j) * 72 + k] = (bf16)bv[j];
    }
    __syncthreads();
#pragma unroll
    for (int kx = 0; kx < 2; ++kx) {
      bf16x8 af[4], bfr[4];
#pragma unroll
      for (int t = 0; t < 4; ++t) {
        af[t] = *(const bf16x8*)(As + (wr + t * 16 + lr) * 72 + kx * 32 + quad * 8);
        bfr[t] = *(const bf16x8*)(Bs + (wc + t * 16 + lr) * 72 + kx * 32 + quad * 8);
      }
#pragma unroll
      for (int rt = 0; rt < 4; ++rt)
#pragma unroll
        for (int ct = 0; ct < 4; ++ct)
          acc[rt][ct] = __builtin_amdgcn_mfma_f32_16x16x32_bf16(af[rt], bfr[ct],
                                                                acc[rt][ct], 0, 0, 0);
    }
  }
#pragma unroll
  for (int rt = 0; rt < 4; ++rt)
#pragma unroll
    for (int ct = 0; ct < 4; ++ct)
#pragma unroll
      for (int r = 0; r < 4; ++r) {
        int row = m0 + wr + rt * 16 + quad * 4 + r;
        int col = col0 + n0 + wc + ct * 16 + lr;
        Cmat[(size_t)row * ostride + col] = (OT)acc[rt][ct][r];
      }
}

// ---------------------------------------------------------------------------
// V transpose: kv [B*N][512] (v = cols 256..511, head hkv at 256+hkv*64)
//           -> vt [B][HKV][D][N]
__global__ __launch_bounds__(256) void transpose_v(const bf16* __restrict__ kv,
                                                   bf16* __restrict__ vt) {
  __shared__ __align__(16) bf16 lds[64 * 72];
  int nt = blockIdx.x;
  int bh = blockIdx.y;
  int b = bh >> 2, hkv = bh & 3;
  int tid = threadIdx.x;
#pragma unroll
  for (int i = 0; i < 2; ++i) {
    int c = tid + i * 256;
    int tok = c >> 3, off = (c & 7) * 8;
    *(bf16x8*)(lds + tok * 72 + off) =
        *(const bf16x8*)(kv + (size_t)(b * N_ + nt * 64 + tok) * 512 + 256 + hkv * 64 + off);
  }
  __syncthreads();
#pragma unroll
  for (int i = 0; i < 2; ++i) {
    int c = tid + i * 256;
    int d = c >> 3, toff = (c & 7) * 8;
    bf16x8 tv;
#pragma unroll
    for (int j = 0; j < 8; ++j) tv[j] = lds[(toff + j) * 72 + d];
    *(bf16x8*)(vt + ((size_t)bh * 64 + d) * N_ + nt * 64 + toff) = tv;
  }
}

// ---------------------------------------------------------------------------
// Per-head RMSNorm + RoPE, in place (bf16 data, fp32 math). One wave per
// (token, head) 64-vector. q heads get folded QSCALE; k heads don't.
__global__ __launch_bounds__(256) void norm_rope(bf16* __restrict__ q,
                                                 bf16* __restrict__ kv) {
  int wave = threadIdx.x >> 6, lane = threadIdx.x & 63;
  int hid = blockIdx.x * 4 + wave;
  int t = hid / 20;
  int sub = hid - t * 20;
  int n = t & (N_ - 1);
  bf16* ptr;
  float oscale;
  if (sub < 16) {
    ptr = q + ((size_t)t * 16 + sub) * 64;
    oscale = QSCALE;
  } else {
    ptr = kv + (size_t)t * 512 + (sub - 16) * 64;
    oscale = 1.0f;
  }
  float x = (float)ptr[lane];
  float ss = x * x;
  ss += __shfl_xor(ss, 1);
  ss += __shfl_xor(ss, 2);
  ss += __shfl_xor(ss, 4);
  ss += __shfl_xor(ss, 8);
  ss += __shfl_xor(ss, 16);
  ss += __shfl_xor(ss, 32);
  float rn = rsqrtf(ss * (1.0f / 64.0f) + 1.1920929e-07f);
  float xn = x * rn;
  float pr = __shfl_xor(xn, 32);
  float rot = (lane < 32) ? -pr : pr;
  float ang = (float)n * exp2f(-0.41524101186092029f * (float)(lane & 31));
  float sv, cv;
  sincosf(ang, &sv, &cv);
  ptr[lane] = (bf16)((xn * cv + rot * sv) * oscale);
}

// ---------------------------------------------------------------------------
// Causal flash attention with GQA — TRANSPOSED dataflow (S^T / O^T).
//   S^T = K·Q^T   (A = K from Ks[key][d],  B = Q^T via q[qrow][d] loads)
//   O^T = V^T·P^T (A = V^T from Vs[d][key], B = P^T via Ps[qrow][key] loads)
// Round-1 change: drop the min-waves __launch_bounds__ hint. (256,4) made the
// allocator target 64 VGPRs -> spilled the staging+acc state to scratch
// (WRITE_SIZE 16MB->257MB, VGPR 92->64). LDS (36.9KB) caps residency at 4
// blocks/CU regardless, and ~92 VGPRs fits 4 waves/SIMD natively.
__global__ __launch_bounds__(256) void attn(bf16* __restrict__ q,
                                            const bf16* __restrict__ kv,
                                            const bf16* __restrict__ vt) {
  __shared__ __align__(16) bf16 Ks[64 * 72];   // [key][d]
  __shared__ __align__(16) bf16 Vs[64 * 72];   // [d][key]
  __shared__ __align__(16) bf16 Ps[128 * 72];  // [q-row][key], wave-private rows
  int id = blockIdx.x;
  int round = id >> 8, rr = id & 255;
  int xq = rr & 15, h = rr >> 4, b = round;
  int qt = (round == 0) ? xq
         : (round == 1) ? (15 - xq)
         : (round == 2) ? ((xq + 8) & 15)
                        : ((7 - xq) & 15);
  int hkv = h >> 2;
  int tid = threadIdx.x;
  int wave = tid >> 6, lane = tid & 63;
  int quad = lane >> 4, lr = lane & 15;
  int qrow0 = qt * 128 + wave * 32;

  // staging geometry: thread covers rows srow and srow+32 at column soff
  int srow = tid >> 3, soff = (tid & 7) * 8;

  // Q fragments (serve as B-operand = Q^T): lane holds Q[qrow0+rt*16+lr][kx*32+quad*8..]
  bf16x8 qf[2][2];
#pragma unroll
  for (int rt = 0; rt < 2; ++rt)
#pragma unroll
    for (int kx = 0; kx < 2; ++kx)
      qf[rt][kx] = *(const bf16x8*)(
          q + ((size_t)(b * N_ + qrow0 + rt * 16 + lr) * H_ + h) * D_ + kx * 32 + quad * 8);

  f32x4 acc[2][4];  // acc[rt][dt] = O^T tile: row d=dt*16+quad*4+r, col qrow=rt*16+lr
  const f32x4 z = {0.f, 0.f, 0.f, 0.f};
  float m_i[2], l_i[2];  // per-lane scalars (q-row = qrow0 + rt*16 + lr)
#pragma unroll
  for (int rt = 0; rt < 2; ++rt) {
#pragma unroll
    for (int dt = 0; dt < 4; ++dt) acc[rt][dt] = z;
    m_i[rt] = NEGINF;
    l_i[rt] = 0.f;
  }

  int nkt = qt * 2 + 2;

  // ---- prologue: stage tile 0 synchronously
  bf16x8 sk0, sk1, sv0, sv1;
  {
    sk0 = *(const bf16x8*)(kv + (size_t)(b * N_ + srow) * 512 + hkv * 64 + soff);
    sk1 = *(const bf16x8*)(kv + (size_t)(b * N_ + srow + 32) * 512 + hkv * 64 + soff);
    sv0 = *(const bf16x8*)(vt + ((size_t)(b * HKV_ + hkv) * 64 + srow) * N_ + soff);
    sv1 = *(const bf16x8*)(vt + ((size_t)(b * HKV_ + hkv) * 64 + srow + 32) * N_ + soff);
    *(bf16x8*)(Ks + srow * 72 + soff) = sk0;
    *(bf16x8*)(Ks + (srow + 32) * 72 + soff) = sk1;
    *(bf16x8*)(Vs + srow * 72 + soff) = sv0;
    *(bf16x8*)(Vs + (srow + 32) * 72 + soff) = sv1;
  }
  asm volatile("s_waitcnt lgkmcnt(0)" ::: "memory");
  __builtin_amdgcn_s_barrier();
  __builtin_amdgcn_sched_barrier(0);

  for (int kt = 0; kt < nkt; ++kt) {
    // ---- issue NEXT tile's global loads early (in flight across compute)
    bool pf = (kt + 1 < nkt);
    if (pf) {
      int krow = (kt + 1) * 64;
      sk0 = *(const bf16x8*)(kv + (size_t)(b * N_ + krow + srow) * 512 + hkv * 64 + soff);
      sk1 = *(const bf16x8*)(kv + (size_t)(b * N_ + krow + srow + 32) * 512 + hkv * 64 + soff);
      sv0 = *(const bf16x8*)(vt + ((size_t)(b * HKV_ + hkv) * 64 + srow) * N_ + krow + soff);
      sv1 = *(const bf16x8*)(vt + ((size_t)(b * HKV_ + hkv) * 64 + srow + 32) * N_ + krow + soff);
    }

    if (kt * 64 <= qrow0 + 31) {
      // S^T = K·Q^T: st[rt][ct] — key = kt*64 + ct*16 + quad*4 + r, qrow col = lr
      f32x4 st[2][4];
#pragma unroll
      for (int rt = 0; rt < 2; ++rt)
#pragma unroll
        for (int ct = 0; ct < 4; ++ct) st[rt][ct] = z;
#pragma unroll
      for (int kx = 0; kx < 2; ++kx) {
        bf16x8 kf[4];
#pragma unroll
        for (int ct = 0; ct < 4; ++ct)
          kf[ct] = *(const bf16x8*)(Ks + (ct * 16 + lr) * 72 + kx * 32 + quad * 8);
        __builtin_amdgcn_s_setprio(1);
#pragma unroll
        for (int rt = 0; rt < 2; ++rt)
#pragma unroll
          for (int ct = 0; ct < 4; ++ct)
            st[rt][ct] = __builtin_amdgcn_mfma_f32_16x16x32_bf16(kf[ct], qf[rt][kx],
                                                                 st[rt][ct], 0, 0, 0);
        __builtin_amdgcn_s_setprio(0);
      }
      // Causal mask (diagonal-crossing tiles only): mask key > qrow
      if (kt * 64 + 63 > qrow0) {
#pragma unroll
        for (int rt = 0; rt < 2; ++rt) {
          int qrow = qrow0 + rt * 16 + lr;
#pragma unroll
          for (int ct = 0; ct < 4; ++ct)
#pragma unroll
            for (int r = 0; r < 4; ++r) {
              int key = kt * 64 + ct * 16 + quad * 4 + r;
              if (key > qrow) st[rt][ct][r] = NEGINF;
            }
        }
      }
      // Online softmax: per-lane scalar state, 2+2 shuffles total per rt
#pragma unroll
      for (int rt = 0; rt < 2; ++rt) {
        float mx = NEGINF;
#pragma unroll
        for (int ct = 0; ct < 4; ++ct)
#pragma unroll
          for (int r = 0; r < 4; ++r) mx = fmaxf(mx, st[rt][ct][r]);
        mx = fmaxf(mx, __shfl_xor(mx, 16));
        mx = fmaxf(mx, __shfl_xor(mx, 32));
        float mnew = fmaxf(m_i[rt], mx);
        float alpha = exp2f(m_i[rt] - mnew);
        m_i[rt] = mnew;
        float rs = 0.f;
#pragma unroll
        for (int ct = 0; ct < 4; ++ct)
#pragma unroll
          for (int r = 0; r < 4; ++r) {
            float p = exp2f(st[rt][ct][r] - mnew);
            st[rt][ct][r] = p;
            rs += p;
          }
        rs += __shfl_xor(rs, 16);
        rs += __shfl_xor(rs, 32);
        l_i[rt] = l_i[rt] * alpha + rs;
#pragma unroll
        for (int dt = 0; dt < 4; ++dt)
#pragma unroll
          for (int r = 0; r < 4; ++r) acc[rt][dt][r] *= alpha;
        // P^T -> Ps[qrow][key]: b64 vector writes (keys quad*4+r contiguous)
#pragma unroll
        for (int ct = 0; ct < 4; ++ct) {
          bf16x4 pk;
#pragma unroll
          for (int r = 0; r < 4; ++r) pk[r] = (bf16)st[rt][ct][r];
          *(bf16x4*)(Ps + (wave * 32 + rt * 16 + lr) * 72 + ct * 16 + quad * 4) = pk;
        }
      }
      // Wave-local LDS ordering (rows wave-private, guard wave-uniform)
      asm volatile("s_waitcnt lgkmcnt(0)" ::: "memory");
      // O^T += V^T·P^T
#pragma unroll
      for (int kx = 0; kx < 2; ++kx) {
        bf16x8 vf[4], pfr[2];
#pragma unroll
        for (int dt = 0; dt < 4; ++dt)
          vf[dt] = *(const bf16x8*)(Vs + (dt * 16 + lr) * 72 + kx * 32 + quad * 8);
#pragma unroll
        for (int rt = 0; rt < 2; ++rt)
          pfr[rt] = *(const bf16x8*)(Ps + (wave * 32 + rt * 16 + lr) * 72 + kx * 32 + quad * 8);
        __builtin_amdgcn_s_setprio(1);
#pragma unroll
        for (int rt = 0; rt < 2; ++rt)
#pragma unroll
          for (int dt = 0; dt < 4; ++dt)
            acc[rt][dt] = __builtin_amdgcn_mfma_f32_16x16x32_bf16(vf[dt], pfr[rt],
                                                                  acc[rt][dt], 0, 0, 0);
        __builtin_amdgcn_s_setprio(0);
      }
    }

    // ---- all waves done READING tile kt (LDS reads already consumed; no
    // vmcnt drain here — prefetch loads stay in flight across the barrier)
    __builtin_amdgcn_s_barrier();
    __builtin_amdgcn_sched_barrier(0);
    if (pf) {
      // compiler inserts s_waitcnt vmcnt(0) before first use of sk*/sv*
      *(bf16x8*)(Ks + srow * 72 + soff) = sk0;
      *(bf16x8*)(Ks + (srow + 32) * 72 + soff) = sk1;
      *(bf16x8*)(Vs + srow * 72 + soff) = sv0;
      *(bf16x8*)(Vs + (srow + 32) * 72 + soff) = sv1;
      asm volatile("s_waitcnt lgkmcnt(0)" ::: "memory");
    }
    __builtin_amdgcn_s_barrier();  // tile kt+1 visible to all waves
    __builtin_amdgcn_sched_barrier(0);
  }

  // Epilogue: y = O / l — O^T layout => lane owns q-row (rt, lr), d = dt*16+quad*4+r
#pragma unroll
  for (int rt = 0; rt < 2; ++rt) {
    float inv = 1.0f / l_i[rt];
    int qrow = qrow0 + rt * 16 + lr;
#pragma unroll
    for (int dt = 0; dt < 4; ++dt) {
      bf16x4 ov;
#pragma unroll
      for (int r = 0; r < 4; ++r) ov[r] = (bf16)(acc[rt][dt][r] * inv);
      *(bf16x4*)(q + ((size_t)(b * N_ + qrow) * H_ + h) * D_ + dt * 16 + quad * 4) = ov;
    }
  }
}

// ---------------------------------------------------------------------------
extern "C" void kernel_launch(void* const* d_in, const int* in_sizes, int n_in,
                              void* d_out, int out_size, void* d_ws, size_t ws_size,
                              hipStream_t stream) {
  // Inputs FP32; output FP32 (verified round 9). Intermediates bf16.
  const float* x = (const float*)d_in[0];
  const float* wq = (const float*)d_in[1];
  const float* wk = (const float*)d_in[2];
  const float* wv = (const float*)d_in[3];
  const float* wo = (const float*)d_in[4];
  float* out = (float*)d_out;
  char* ws = (char*)d_ws;
  // ws (28 MB): q/y 16 MB [0,16M) | kv 8 MB [16M,24M) | vt 4 MB [24M,28M)
  bf16* q = (bf16*)(ws);
  bf16* kv = (bf16*)(ws + 16777216);
  bf16* vt = (bf16*)(ws + 25165824);

  gemm_any<float, bf16><<<dim3(64, 8), 256, 0, stream>>>(x, wq, q, 8192, 1024, 1024, 1024, 0);
  gemm_any<float, bf16><<<dim3(64, 2), 256, 0, stream>>>(x, wk, kv, 8192, 1024, 256, 512, 0);
  gemm_any<float, bf16><<<dim3(64, 2), 256, 0, stream>>>(x, wv, kv, 8192, 1024, 256, 512, 256);
  norm_rope<<<dim3(40960), 256, 0, stream>>>(q, kv);
  transpose_v<<<dim3(32, 16), 256, 0, stream>>>(kv, vt);
  attn<<<dim3(1024), 256, 0, stream>>>(q, kv, vt);
  gemm_any<bf16, float><<<dim3(64, 8), 256, 0, stream>>>(q, wo, out, 8192, 1024, 1024, 1024, 0);
}

// Round 3
// 420.504 us; speedup vs baseline: 1.4064x; 1.2190x over previous
//
#include <hip/hip_runtime.h>

typedef __bf16 bf16;
typedef __bf16 bf16x8 __attribute__((ext_vector_type(8)));
typedef __bf16 bf16x4 __attribute__((ext_vector_type(4)));
typedef float f32x4 __attribute__((ext_vector_type(4)));

#define B_ 4
#define N_ 2048
#define C_ 1024
#define H_ 16
#define HKV_ 4
#define D_ 64

// fold: 1.5 (qk_gain) * 0.125 (1/sqrt(64)) * log2(e)  -> use exp2f in softmax
#define QSCALE 0.2705053201666806f
#define NEGINF (-1.0e30f)

// work queue for persistent attn (reset by transpose_v each launch)
__device__ int g_ctr;

// ---------------------------------------------------------------------------
// GEMM: C[M][.] = A[M][K] * B[K][.].  (generic version, used for the wo GEMM)
template <typename AT, typename OT>
__global__ __launch_bounds__(256) void gemm_any(const AT* __restrict__ A,
                                                const float* __restrict__ B,
                                                OT* __restrict__ Cmat,
                                                int M, int K, int bn_stride,
                                                int ostride, int col0) {
  __shared__ __align__(16) bf16 As[128 * 72];
  __shared__ __align__(16) bf16 Bs[128 * 72];
  int m0 = blockIdx.x * 128, n0 = blockIdx.y * 128;
  int tid = threadIdx.x;
  int wave = tid >> 6, lane = tid & 63;
  int quad = lane >> 4, lr = lane & 15;
  int wr = (wave >> 1) * 64, wc = (wave & 1) * 64;

  f32x4 acc[4][4];
  const f32x4 z = {0.f, 0.f, 0.f, 0.f};
#pragma unroll
  for (int i = 0; i < 4; ++i)
#pragma unroll
    for (int j = 0; j < 4; ++j) acc[i][j] = z;

  for (int k0 = 0; k0 < K; k0 += 64) {
    __syncthreads();
    if constexpr (sizeof(AT) == 4) {
#pragma unroll
      for (int i = 0; i < 8; ++i) {
        int c = tid + i * 256;
        int row = c >> 4, off4 = (c & 15) * 4;
        f32x4 av = *(const f32x4*)(A + (size_t)(m0 + row) * K + k0 + off4);
        bf16x4 a16;
#pragma unroll
        for (int j = 0; j < 4; ++j) a16[j] = (bf16)av[j];
        *(bf16x4*)(As + row * 72 + off4) = a16;
      }
    } else {
#pragma unroll
      for (int i = 0; i < 4; ++i) {
        int c = tid + i * 256;
        int row = c >> 3, off = (c & 7) * 8;
        *(bf16x8*)(As + row * 72 + off) =
            *(const bf16x8*)(A + (size_t)(m0 + row) * K + k0 + off);
      }
    }
#pragma unroll
    for (int i = 0; i < 8; ++i) {
      int c = tid + i * 256;
      int k = c >> 5, n4 = (c & 31) * 4;
      f32x4 bv = *(const f32x4*)(B + (size_t)(k0 + k) * bn_stride + n0 + n4);
#pragma unroll
      for (int j = 0; j < 4; ++j) Bs[(n4 + j) * 72 + k] = (bf16)bv[j];
    }
    __syncthreads();
#pragma unroll
    for (int kx = 0; kx < 2; ++kx) {
      bf16x8 af[4], bfr[4];
#pragma unroll
      for (int t = 0; t < 4; ++t) {
        af[t] = *(const bf16x8*)(As + (wr + t * 16 + lr) * 72 + kx * 32 + quad * 8);
        bfr[t] = *(const bf16x8*)(Bs + (wc + t * 16 + lr) * 72 + kx * 32 + quad * 8);
      }
#pragma unroll
      for (int rt = 0; rt < 4; ++rt)
#pragma unroll
        for (int ct = 0; ct < 4; ++ct)
          acc[rt][ct] = __builtin_amdgcn_mfma_f32_16x16x32_bf16(af[rt], bfr[ct],
                                                                acc[rt][ct], 0, 0, 0);
    }
  }
#pragma unroll
  for (int rt = 0; rt < 4; ++rt)
#pragma unroll
    for (int ct = 0; ct < 4; ++ct)
#pragma unroll
      for (int r = 0; r < 4; ++r) {
        int row = m0 + wr + rt * 16 + quad * 4 + r;
        int col = col0 + n0 + wc + ct * 16 + lr;
        Cmat[(size_t)row * ostride + col] = (OT)acc[rt][ct][r];
      }
}

// ---------------------------------------------------------------------------
// Fused QKV projection: one launch, grid (64, 12).
//   by 0..7  -> wq -> q   cols by*128,        ostride 1024
//   by 8..9  -> wk -> kv  cols (by-8)*128,    ostride 512
//   by 10..11-> wv -> kv  cols 256+(by-10)*128
// Same math/accumulation order as the previous 3 separate GEMMs.
__global__ __launch_bounds__(256) void gemm_qkv(const float* __restrict__ x,
                                                const float* __restrict__ wq,
                                                const float* __restrict__ wk,
                                                const float* __restrict__ wv,
                                                bf16* __restrict__ qb,
                                                bf16* __restrict__ kvb) {
  __shared__ __align__(16) bf16 As[128 * 72];
  __shared__ __align__(16) bf16 Bs[128 * 72];
  int by = blockIdx.y;
  const float* Bp;
  bf16* Out;
  int bns, ostride, bcol0, ocol0;
  if (by < 8) {
    Bp = wq; bns = 1024; bcol0 = by * 128; Out = qb; ocol0 = bcol0; ostride = 1024;
  } else if (by < 10) {
    Bp = wk; bns = 256; bcol0 = (by - 8) * 128; Out = kvb; ocol0 = bcol0; ostride = 512;
  } else {
    Bp = wv; bns = 256; bcol0 = (by - 10) * 128; Out = kvb; ocol0 = 256 + bcol0; ostride = 512;
  }
  int m0 = blockIdx.x * 128;
  int tid = threadIdx.x;
  int wave = tid >> 6, lane = tid & 63;
  int quad = lane >> 4, lr = lane & 15;
  int wr = (wave >> 1) * 64, wc = (wave & 1) * 64;

  f32x4 acc[4][4];
  const f32x4 z = {0.f, 0.f, 0.f, 0.f};
#pragma unroll
  for (int i = 0; i < 4; ++i)
#pragma unroll
    for (int j = 0; j < 4; ++j) acc[i][j] = z;

  for (int k0 = 0; k0 < 1024; k0 += 64) {
    __syncthreads();
#pragma unroll
    for (int i = 0; i < 8; ++i) {
      int c = tid + i * 256;
      int row = c >> 4, off4 = (c & 15) * 4;
      f32x4 av = *(const f32x4*)(x + (size_t)(m0 + row) * 1024 + k0 + off4);
      bf16x4 a16;
#pragma unroll
      for (int j = 0; j < 4; ++j) a16[j] = (bf16)av[j];
      *(bf16x4*)(As + row * 72 + off4) = a16;
    }
#pragma unroll
    for (int i = 0; i < 8; ++i) {
      int c = tid + i * 256;
      int k = c >> 5, n4 = (c & 31) * 4;
      f32x4 bv = *(const f32x4*)(Bp + (size_t)(k0 + k) * bns + bcol0 + n4);
#pragma unroll
      for (int j = 0; j < 4; ++j) Bs[(n4 + j) * 72 + k] = (bf16)bv[j];
    }
    __syncthreads();
#pragma unroll
    for (int kx = 0; kx < 2; ++kx) {
      bf16x8 af[4], bfr[4];
#pragma unroll
      for (int t = 0; t < 4; ++t) {
        af[t] = *(const bf16x8*)(As + (wr + t * 16 + lr) * 72 + kx * 32 + quad * 8);
        bfr[t] = *(const bf16x8*)(Bs + (wc + t * 16 + lr) * 72 + kx * 32 + quad * 8);
      }
#pragma unroll
      for (int rt = 0; rt < 4; ++rt)
#pragma unroll
        for (int ct = 0; ct < 4; ++ct)
          acc[rt][ct] = __builtin_amdgcn_mfma_f32_16x16x32_bf16(af[rt], bfr[ct],
                                                                acc[rt][ct], 0, 0, 0);
    }
  }
#pragma unroll
  for (int rt = 0; rt < 4; ++rt)
#pragma unroll
    for (int ct = 0; ct < 4; ++ct)
#pragma unroll
      for (int r = 0; r < 4; ++r) {
        int row = m0 + wr + rt * 16 + quad * 4 + r;
        int col = ocol0 + wc + ct * 16 + lr;
        Out[(size_t)row * ostride + col] = (bf16)acc[rt][ct][r];
      }
}

// ---------------------------------------------------------------------------
// V transpose: kv [B*N][512] (v = cols 256..511, head hkv at 256+hkv*64)
//           -> vt [B][HKV][D][N].  Also resets the attn work-queue counter.
__global__ __launch_bounds__(256) void transpose_v(const bf16* __restrict__ kv,
                                                   bf16* __restrict__ vt) {
  __shared__ __align__(16) bf16 lds[64 * 72];
  if (blockIdx.x == 0 && blockIdx.y == 0 && threadIdx.x == 0) g_ctr = 0;
  int nt = blockIdx.x;
  int bh = blockIdx.y;
  int b = bh >> 2, hkv = bh & 3;
  int tid = threadIdx.x;
#pragma unroll
  for (int i = 0; i < 2; ++i) {
    int c = tid + i * 256;
    int tok = c >> 3, off = (c & 7) * 8;
    *(bf16x8*)(lds + tok * 72 + off) =
        *(const bf16x8*)(kv + (size_t)(b * N_ + nt * 64 + tok) * 512 + 256 + hkv * 64 + off);
  }
  __syncthreads();
#pragma unroll
  for (int i = 0; i < 2; ++i) {
    int c = tid + i * 256;
    int d = c >> 3, toff = (c & 7) * 8;
    bf16x8 tv;
#pragma unroll
    for (int j = 0; j < 8; ++j) tv[j] = lds[(toff + j) * 72 + d];
    *(bf16x8*)(vt + ((size_t)bh * 64 + d) * N_ + nt * 64 + toff) = tv;
  }
}

// ---------------------------------------------------------------------------
// Per-head RMSNorm + RoPE, in place (bf16 data, fp32 math). One wave per
// (token, head) 64-vector. q heads get folded QSCALE; k heads don't.
__global__ __launch_bounds__(256) void norm_rope(bf16* __restrict__ q,
                                                 bf16* __restrict__ kv) {
  int wave = threadIdx.x >> 6, lane = threadIdx.x & 63;
  int hid = blockIdx.x * 4 + wave;
  int t = hid / 20;
  int sub = hid - t * 20;
  int n = t & (N_ - 1);
  bf16* ptr;
  float oscale;
  if (sub < 16) {
    ptr = q + ((size_t)t * 16 + sub) * 64;
    oscale = QSCALE;
  } else {
    ptr = kv + (size_t)t * 512 + (sub - 16) * 64;
    oscale = 1.0f;
  }
  float x = (float)ptr[lane];
  float ss = x * x;
  ss += __shfl_xor(ss, 1);
  ss += __shfl_xor(ss, 2);
  ss += __shfl_xor(ss, 4);
  ss += __shfl_xor(ss, 8);
  ss += __shfl_xor(ss, 16);
  ss += __shfl_xor(ss, 32);
  float rn = rsqrtf(ss * (1.0f / 64.0f) + 1.1920929e-07f);
  float xn = x * rn;
  float pr = __shfl_xor(xn, 32);
  float rot = (lane < 32) ? -pr : pr;
  float ang = (float)n * exp2f(-0.41524101186092029f * (float)(lane & 31));
  float sv, cv;
  sincosf(ang, &sv, &cv);
  ptr[lane] = (bf16)((xn * cv + rot * sv) * oscale);
}

// ---------------------------------------------------------------------------
// Causal flash attention with GQA — TRANSPOSED dataflow (S^T / O^T),
// PERSISTENT work-queue version.
//   Item = (b, h, j) where j = 64-row q-tile index (0..31). nkt = j+1 k-tiles.
//   2048 items handed out longest-first (LPT) via global atomic to 1280
//   persistent block slots (~4-5/CU resident until the queue drains) —
//   removes the static-assignment tail that held occupancy at 15%.
//   Each wave owns 16 q-rows; every wave computes every k-tile (only the
//   diagonal tile kt==j needs masking), so block barriers stay uniform.
__global__ __launch_bounds__(256) void attn(bf16* __restrict__ q,
                                            const bf16* __restrict__ kv,
                                            const bf16* __restrict__ vt) {
  __shared__ __align__(16) bf16 Ks[64 * 72];  // [key][d]
  __shared__ __align__(16) bf16 Vs[64 * 72];  // [d][key]
  __shared__ __align__(16) bf16 Ps[64 * 72];  // [q-row][key], wave-private rows
  __shared__ int s_item;
  int tid = threadIdx.x;
  int wave = tid >> 6, lane = tid & 63;
  int quad = lane >> 4, lr = lane & 15;
  int srow = tid >> 3, soff = (tid & 7) * 8;
  const f32x4 z = {0.f, 0.f, 0.f, 0.f};

  while (true) {
    if (tid == 0) s_item = atomicAdd(&g_ctr, 1);
    __syncthreads();  // publish s_item; also: all waves done with prev item's LDS
    int item = s_item;
    if (item >= 2048) break;
    int j = 31 - (item >> 6);  // 64-row q-tile index, longest first
    int rr = item & 63;
    int b = rr & 3, h = rr >> 2, hkv = h >> 2;
    int qrow0 = j * 64 + wave * 16;  // this wave's first q-row
    int nkt = j + 1;

    // Q fragments (B-operand = Q^T): lane holds Q[qrow0+lr][kx*32+quad*8..]
    bf16x8 qf[2];
#pragma unroll
    for (int kx = 0; kx < 2; ++kx)
      qf[kx] = *(const bf16x8*)(
          q + ((size_t)(b * N_ + qrow0 + lr) * H_ + h) * D_ + kx * 32 + quad * 8);

    f32x4 acc[4];  // acc[dt] = O^T tile: row d=dt*16+quad*4+r, col qrow=lr
    float m_i = NEGINF, l_i = 0.f;
#pragma unroll
    for (int dt = 0; dt < 4; ++dt) acc[dt] = z;

    // ---- prologue: stage tile 0 synchronously
    bf16x8 sk0, sk1, sv0, sv1;
    sk0 = *(const bf16x8*)(kv + (size_t)(b * N_ + srow) * 512 + hkv * 64 + soff);
    sk1 = *(const bf16x8*)(kv + (size_t)(b * N_ + srow + 32) * 512 + hkv * 64 + soff);
    sv0 = *(const bf16x8*)(vt + ((size_t)(b * HKV_ + hkv) * 64 + srow) * N_ + soff);
    sv1 = *(const bf16x8*)(vt + ((size_t)(b * HKV_ + hkv) * 64 + srow + 32) * N_ + soff);
    *(bf16x8*)(Ks + srow * 72 + soff) = sk0;
    *(bf16x8*)(Ks + (srow + 32) * 72 + soff) = sk1;
    *(bf16x8*)(Vs + srow * 72 + soff) = sv0;
    *(bf16x8*)(Vs + (srow + 32) * 72 + soff) = sv1;
    asm volatile("s_waitcnt lgkmcnt(0)" ::: "memory");
    __builtin_amdgcn_s_barrier();
    __builtin_amdgcn_sched_barrier(0);

    for (int kt = 0; kt < nkt; ++kt) {
      // ---- issue NEXT tile's global loads early (in flight across compute)
      bool pf = (kt + 1 < nkt);
      if (pf) {
        int krow = (kt + 1) * 64;
        sk0 = *(const bf16x8*)(kv + (size_t)(b * N_ + krow + srow) * 512 + hkv * 64 + soff);
        sk1 = *(const bf16x8*)(kv + (size_t)(b * N_ + krow + srow + 32) * 512 + hkv * 64 + soff);
        sv0 = *(const bf16x8*)(vt + ((size_t)(b * HKV_ + hkv) * 64 + srow) * N_ + krow + soff);
        sv1 = *(const bf16x8*)(vt + ((size_t)(b * HKV_ + hkv) * 64 + srow + 32) * N_ + krow + soff);
      }

      // S^T = K·Q^T: st[ct] — key = kt*64 + ct*16 + quad*4 + r, qrow col = lr
      f32x4 st[4];
#pragma unroll
      for (int ct = 0; ct < 4; ++ct) st[ct] = z;
#pragma unroll
      for (int kx = 0; kx < 2; ++kx) {
        bf16x8 kf[4];
#pragma unroll
        for (int ct = 0; ct < 4; ++ct)
          kf[ct] = *(const bf16x8*)(Ks + (ct * 16 + lr) * 72 + kx * 32 + quad * 8);
        __builtin_amdgcn_s_setprio(1);
#pragma unroll
        for (int ct = 0; ct < 4; ++ct)
          st[ct] = __builtin_amdgcn_mfma_f32_16x16x32_bf16(kf[ct], qf[kx], st[ct], 0, 0, 0);
        __builtin_amdgcn_s_setprio(0);
      }
      // Causal mask — only the diagonal tile kt == j crosses the diagonal
      if (kt == j) {
        int qrow = qrow0 + lr;
#pragma unroll
        for (int ct = 0; ct < 4; ++ct)
#pragma unroll
          for (int r = 0; r < 4; ++r) {
            int key = kt * 64 + ct * 16 + quad * 4 + r;
            if (key > qrow) st[ct][r] = NEGINF;
          }
      }
      // Online softmax: per-lane scalar state, 2+2 shuffles
      float mx = NEGINF;
#pragma unroll
      for (int ct = 0; ct < 4; ++ct)
#pragma unroll
        for (int r = 0; r < 4; ++r) mx = fmaxf(mx, st[ct][r]);
      mx = fmaxf(mx, __shfl_xor(mx, 16));
      mx = fmaxf(mx, __shfl_xor(mx, 32));
      float mnew = fmaxf(m_i, mx);
      float alpha = exp2f(m_i - mnew);
      m_i = mnew;
      float rs = 0.f;
#pragma unroll
      for (int ct = 0; ct < 4; ++ct)
#pragma unroll
        for (int r = 0; r < 4; ++r) {
          float p = exp2f(st[ct][r] - mnew);
          st[ct][r] = p;
          rs += p;
        }
      rs += __shfl_xor(rs, 16);
      rs += __shfl_xor(rs, 32);
      l_i = l_i * alpha + rs;
#pragma unroll
      for (int dt = 0; dt < 4; ++dt)
#pragma unroll
        for (int r = 0; r < 4; ++r) acc[dt][r] *= alpha;
      // P^T -> Ps[qrow][key]: b64 vector writes (keys quad*4+r contiguous)
#pragma unroll
      for (int ct = 0; ct < 4; ++ct) {
        bf16x4 pk;
#pragma unroll
        for (int r = 0; r < 4; ++r) pk[r] = (bf16)st[ct][r];
        *(bf16x4*)(Ps + (wave * 16 + lr) * 72 + ct * 16 + quad * 4) = pk;
      }
      // Wave-local LDS ordering (rows wave-private, guard wave-uniform)
      asm volatile("s_waitcnt lgkmcnt(0)" ::: "memory");
      // O^T += V^T·P^T
#pragma unroll
      for (int kx = 0; kx < 2; ++kx) {
        bf16x8 vf[4], pfr;
#pragma unroll
        for (int dt = 0; dt < 4; ++dt)
          vf[dt] = *(const bf16x8*)(Vs + (dt * 16 + lr) * 72 + kx * 32 + quad * 8);
        pfr = *(const bf16x8*)(Ps + (wave * 16 + lr) * 72 + kx * 32 + quad * 8);
        __builtin_amdgcn_s_setprio(1);
#pragma unroll
        for (int dt = 0; dt < 4; ++dt)
          acc[dt] = __builtin_amdgcn_mfma_f32_16x16x32_bf16(vf[dt], pfr, acc[dt], 0, 0, 0);
        __builtin_amdgcn_s_setprio(0);
      }

      // ---- all waves done READING tile kt; prefetch loads stay in flight
      __builtin_amdgcn_s_barrier();
      __builtin_amdgcn_sched_barrier(0);
      if (pf) {
        // compiler inserts s_waitcnt vmcnt(0) before first use of sk*/sv*
        *(bf16x8*)(Ks + srow * 72 + soff) = sk0;
        *(bf16x8*)(Ks + (srow + 32) * 72 + soff) = sk1;
        *(bf16x8*)(Vs + srow * 72 + soff) = sv0;
        *(bf16x8*)(Vs + (srow + 32) * 72 + soff) = sv1;
        asm volatile("s_waitcnt lgkmcnt(0)" ::: "memory");
      }
      __builtin_amdgcn_s_barrier();  // tile kt+1 visible to all waves
      __builtin_amdgcn_sched_barrier(0);
    }

    // Epilogue: y = O / l — lane owns q-row lr, d = dt*16+quad*4+r
    float inv = 1.0f / l_i;
    int qrow = qrow0 + lr;
#pragma unroll
    for (int dt = 0; dt < 4; ++dt) {
      bf16x4 ov;
#pragma unroll
      for (int r = 0; r < 4; ++r) ov[r] = (bf16)(acc[dt][r] * inv);
      *(bf16x4*)(q + ((size_t)(b * N_ + qrow) * H_ + h) * D_ + dt * 16 + quad * 4) = ov;
    }
  }
}

// ---------------------------------------------------------------------------
extern "C" void kernel_launch(void* const* d_in, const int* in_sizes, int n_in,
                              void* d_out, int out_size, void* d_ws, size_t ws_size,
                              hipStream_t stream) {
  // Inputs FP32; output FP32. Intermediates bf16.
  const float* x = (const float*)d_in[0];
  const float* wq = (const float*)d_in[1];
  const float* wk = (const float*)d_in[2];
  const float* wv = (const float*)d_in[3];
  const float* wo = (const float*)d_in[4];
  float* out = (float*)d_out;
  char* ws = (char*)d_ws;
  // ws (28 MB): q/y 16 MB [0,16M) | kv 8 MB [16M,24M) | vt 4 MB [24M,28M)
  bf16* q = (bf16*)(ws);
  bf16* kv = (bf16*)(ws + 16777216);
  bf16* vt = (bf16*)(ws + 25165824);

  gemm_qkv<<<dim3(64, 12), 256, 0, stream>>>(x, wq, wk, wv, q, kv);
  norm_rope<<<dim3(40960), 256, 0, stream>>>(q, kv);
  transpose_v<<<dim3(32, 16), 256, 0, stream>>>(kv, vt);
  attn<<<dim3(1280), 256, 0, stream>>>(q, kv, vt);
  gemm_any<bf16, float><<<dim3(64, 8), 256, 0, stream>>>(q, wo, out, 8192, 1024, 1024, 1024, 0);
}

// Round 4
// 299.136 us; speedup vs baseline: 1.9770x; 1.4057x over previous
//
#include <hip/hip_runtime.h>

typedef __bf16 bf16;
typedef __bf16 bf16x8 __attribute__((ext_vector_type(8)));
typedef __bf16 bf16x4 __attribute__((ext_vector_type(4)));
typedef float f32x4 __attribute__((ext_vector_type(4)));

#define B_ 4
#define N_ 2048
#define C_ 1024
#define H_ 16
#define HKV_ 4
#define D_ 64

// fold: 1.5 (qk_gain) * 0.125 (1/sqrt(64)) * log2(e)  -> use exp2f in softmax
#define QSCALE 0.2705053201666806f
#define NEGINF (-1.0e30f)

// work queue for persistent attn (reset by transpose_v each launch)
__device__ int g_ctr;

// ---------------------------------------------------------------------------
// Weight prep: w [1024 k][ncols n] f32 -> wT [n][1024 k] bf16 (+ convert).
// Hoists the per-k-step scalar LDS transpose (50M bank-conflict cycles per
// GEMM dispatch in round 3) out of the GEMM loop entirely. One-shot, ~3 MB.
// Fused qkv variant: wq (256 tiles) | wk (64) | wv (64) -> wT rows
// [0,1024) | [1024,1280) | [1280,1536).
__global__ __launch_bounds__(256) void prep_qkv(const float* __restrict__ wq,
                                                const float* __restrict__ wk,
                                                const float* __restrict__ wv,
                                                bf16* __restrict__ wT) {
  __shared__ __align__(16) bf16 lds[64 * 72];
  int bx = blockIdx.x;
  const float* w;
  int ncols, tk, tn, nbase;
  if (bx < 256) {
    w = wq; ncols = 1024; tk = bx >> 4; tn = bx & 15; nbase = 0;
  } else if (bx < 320) {
    int t = bx - 256;
    w = wk; ncols = 256; tk = t >> 2; tn = t & 3; nbase = 1024;
  } else {
    int t = bx - 320;
    w = wv; ncols = 256; tk = t >> 2; tn = t & 3; nbase = 1280;
  }
  int tid = threadIdx.x;
#pragma unroll
  for (int i = 0; i < 4; ++i) {
    int c = tid + i * 256;
    int kr = c >> 4, n4 = (c & 15) * 4;
    f32x4 v = *(const f32x4*)(w + (size_t)(tk * 64 + kr) * ncols + tn * 64 + n4);
    bf16x4 b;
#pragma unroll
    for (int j = 0; j < 4; ++j) b[j] = (bf16)v[j];
    *(bf16x4*)(lds + kr * 72 + n4) = b;
  }
  __syncthreads();
#pragma unroll
  for (int i = 0; i < 2; ++i) {
    int c = tid + i * 256;
    int n = c >> 3, koff = (c & 7) * 8;
    bf16x8 tv;
#pragma unroll
    for (int j = 0; j < 8; ++j) tv[j] = lds[(koff + j) * 72 + n];
    *(bf16x8*)(wT + (size_t)(nbase + tn * 64 + n) * 1024 + tk * 64 + koff) = tv;
  }
}

// Single-matrix variant for wo (1024x1024), launched after attn (aliases vt).
__global__ __launch_bounds__(256) void prep_wo(const float* __restrict__ w,
                                               bf16* __restrict__ wT) {
  __shared__ __align__(16) bf16 lds[64 * 72];
  int tk = blockIdx.x >> 4, tn = blockIdx.x & 15;
  int tid = threadIdx.x;
#pragma unroll
  for (int i = 0; i < 4; ++i) {
    int c = tid + i * 256;
    int kr = c >> 4, n4 = (c & 15) * 4;
    f32x4 v = *(const f32x4*)(w + (size_t)(tk * 64 + kr) * 1024 + tn * 64 + n4);
    bf16x4 b;
#pragma unroll
    for (int j = 0; j < 4; ++j) b[j] = (bf16)v[j];
    *(bf16x4*)(lds + kr * 72 + n4) = b;
  }
  __syncthreads();
#pragma unroll
  for (int i = 0; i < 2; ++i) {
    int c = tid + i * 256;
    int n = c >> 3, koff = (c & 7) * 8;
    bf16x8 tv;
#pragma unroll
    for (int j = 0; j < 8; ++j) tv[j] = lds[(koff + j) * 72 + n];
    *(bf16x8*)(wT + (size_t)(tn * 64 + n) * 1024 + tk * 64 + koff) = tv;
  }
}

// ---------------------------------------------------------------------------
// Fused QKV projection, bf16 pre-transposed weights. Grid (64, 12).
//   by 0..7  -> q   cols by*128        (ostride 1024)
//   by 8..9  -> kv  cols (by-8)*128    (ostride 512)
//   by 10..11-> kv  cols 256+(by-10)*128
// B-staging is now a conflict-free vectorized copy from wT[n][k].
__global__ __launch_bounds__(256) void gemm_qkv(const float* __restrict__ x,
                                                const bf16* __restrict__ wT,
                                                bf16* __restrict__ qb,
                                                bf16* __restrict__ kvb) {
  __shared__ __align__(16) bf16 As[128 * 72];
  __shared__ __align__(16) bf16 Bs[128 * 72];
  int by = blockIdx.y;
  int n0 = by * 128;  // row into wT[1536][1024]
  bf16* Out;
  int ostride, ocol0;
  if (by < 8) {
    Out = qb; ostride = 1024; ocol0 = by * 128;
  } else if (by < 10) {
    Out = kvb; ostride = 512; ocol0 = (by - 8) * 128;
  } else {
    Out = kvb; ostride = 512; ocol0 = 256 + (by - 10) * 128;
  }
  int m0 = blockIdx.x * 128;
  int tid = threadIdx.x;
  int wave = tid >> 6, lane = tid & 63;
  int quad = lane >> 4, lr = lane & 15;
  int wr = (wave >> 1) * 64, wc = (wave & 1) * 64;

  f32x4 acc[4][4];
  const f32x4 z = {0.f, 0.f, 0.f, 0.f};
#pragma unroll
  for (int i = 0; i < 4; ++i)
#pragma unroll
    for (int j = 0; j < 4; ++j) acc[i][j] = z;

  for (int k0 = 0; k0 < 1024; k0 += 64) {
    __syncthreads();
#pragma unroll
    for (int i = 0; i < 8; ++i) {
      int c = tid + i * 256;
      int row = c >> 4, off4 = (c & 15) * 4;
      f32x4 av = *(const f32x4*)(x + (size_t)(m0 + row) * 1024 + k0 + off4);
      bf16x4 a16;
#pragma unroll
      for (int j = 0; j < 4; ++j) a16[j] = (bf16)av[j];
      *(bf16x4*)(As + row * 72 + off4) = a16;
    }
#pragma unroll
    for (int i = 0; i < 4; ++i) {
      int c = tid + i * 256;
      int row = c >> 3, off = (c & 7) * 8;
      *(bf16x8*)(Bs + row * 72 + off) =
          *(const bf16x8*)(wT + (size_t)(n0 + row) * 1024 + k0 + off);
    }
    __syncthreads();
#pragma unroll
    for (int kx = 0; kx < 2; ++kx) {
      bf16x8 af[4], bfr[4];
#pragma unroll
      for (int t = 0; t < 4; ++t) {
        af[t] = *(const bf16x8*)(As + (wr + t * 16 + lr) * 72 + kx * 32 + quad * 8);
        bfr[t] = *(const bf16x8*)(Bs + (wc + t * 16 + lr) * 72 + kx * 32 + quad * 8);
      }
#pragma unroll
      for (int rt = 0; rt < 4; ++rt)
#pragma unroll
        for (int ct = 0; ct < 4; ++ct)
          acc[rt][ct] = __builtin_amdgcn_mfma_f32_16x16x32_bf16(af[rt], bfr[ct],
                                                                acc[rt][ct], 0, 0, 0);
    }
  }
#pragma unroll
  for (int rt = 0; rt < 4; ++rt)
#pragma unroll
    for (int ct = 0; ct < 4; ++ct)
#pragma unroll
      for (int r = 0; r < 4; ++r) {
        int row = m0 + wr + rt * 16 + quad * 4 + r;
        int col = ocol0 + wc + ct * 16 + lr;
        Out[(size_t)row * ostride + col] = (bf16)acc[rt][ct][r];
      }
}

// ---------------------------------------------------------------------------
// Output projection: A = attn output (bf16, [8192][1024]), B^T = woT bf16
// [n][k], C = float out. Grid (64, 8). Same structure, all-bf16 staging.
__global__ __launch_bounds__(256) void gemm_out(const bf16* __restrict__ A,
                                                const bf16* __restrict__ Bt,
                                                float* __restrict__ C) {
  __shared__ __align__(16) bf16 As[128 * 72];
  __shared__ __align__(16) bf16 Bs[128 * 72];
  int m0 = blockIdx.x * 128, n0 = blockIdx.y * 128;
  int tid = threadIdx.x;
  int wave = tid >> 6, lane = tid & 63;
  int quad = lane >> 4, lr = lane & 15;
  int wr = (wave >> 1) * 64, wc = (wave & 1) * 64;

  f32x4 acc[4][4];
  const f32x4 z = {0.f, 0.f, 0.f, 0.f};
#pragma unroll
  for (int i = 0; i < 4; ++i)
#pragma unroll
    for (int j = 0; j < 4; ++j) acc[i][j] = z;

  for (int k0 = 0; k0 < 1024; k0 += 64) {
    __syncthreads();
#pragma unroll
    for (int i = 0; i < 4; ++i) {
      int c = tid + i * 256;
      int row = c >> 3, off = (c & 7) * 8;
      *(bf16x8*)(As + row * 72 + off) =
          *(const bf16x8*)(A + (size_t)(m0 + row) * 1024 + k0 + off);
      *(bf16x8*)(Bs + row * 72 + off) =
          *(const bf16x8*)(Bt + (size_t)(n0 + row) * 1024 + k0 + off);
    }
    __syncthreads();
#pragma unroll
    for (int kx = 0; kx < 2; ++kx) {
      bf16x8 af[4], bfr[4];
#pragma unroll
      for (int t = 0; t < 4; ++t) {
        af[t] = *(const bf16x8*)(As + (wr + t * 16 + lr) * 72 + kx * 32 + quad * 8);
        bfr[t] = *(const bf16x8*)(Bs + (wc + t * 16 + lr) * 72 + kx * 32 + quad * 8);
      }
#pragma unroll
      for (int rt = 0; rt < 4; ++rt)
#pragma unroll
        for (int ct = 0; ct < 4; ++ct)
          acc[rt][ct] = __builtin_amdgcn_mfma_f32_16x16x32_bf16(af[rt], bfr[ct],
                                                                acc[rt][ct], 0, 0, 0);
    }
  }
#pragma unroll
  for (int rt = 0; rt < 4; ++rt)
#pragma unroll
    for (int ct = 0; ct < 4; ++ct)
#pragma unroll
      for (int r = 0; r < 4; ++r) {
        int row = m0 + wr + rt * 16 + quad * 4 + r;
        int col = n0 + wc + ct * 16 + lr;
        C[(size_t)row * 1024 + col] = acc[rt][ct][r];
      }
}

// ---------------------------------------------------------------------------
// V transpose: kv [B*N][512] (v = cols 256..511, head hkv at 256+hkv*64)
//           -> vt [B][HKV][D][N].  Also resets the attn work-queue counter.
__global__ __launch_bounds__(256) void transpose_v(const bf16* __restrict__ kv,
                                                   bf16* __restrict__ vt) {
  __shared__ __align__(16) bf16 lds[64 * 72];
  if (blockIdx.x == 0 && blockIdx.y == 0 && threadIdx.x == 0) g_ctr = 0;
  int nt = blockIdx.x;
  int bh = blockIdx.y;
  int b = bh >> 2, hkv = bh & 3;
  int tid = threadIdx.x;
#pragma unroll
  for (int i = 0; i < 2; ++i) {
    int c = tid + i * 256;
    int tok = c >> 3, off = (c & 7) * 8;
    *(bf16x8*)(lds + tok * 72 + off) =
        *(const bf16x8*)(kv + (size_t)(b * N_ + nt * 64 + tok) * 512 + 256 + hkv * 64 + off);
  }
  __syncthreads();
#pragma unroll
  for (int i = 0; i < 2; ++i) {
    int c = tid + i * 256;
    int d = c >> 3, toff = (c & 7) * 8;
    bf16x8 tv;
#pragma unroll
    for (int j = 0; j < 8; ++j) tv[j] = lds[(toff + j) * 72 + d];
    *(bf16x8*)(vt + ((size_t)bh * 64 + d) * N_ + nt * 64 + toff) = tv;
  }
}

// ---------------------------------------------------------------------------
// Per-head RMSNorm + RoPE, in place (bf16 data, fp32 math). One wave per
// (token, head) 64-vector. q heads get folded QSCALE; k heads don't.
__global__ __launch_bounds__(256) void norm_rope(bf16* __restrict__ q,
                                                 bf16* __restrict__ kv) {
  int wave = threadIdx.x >> 6, lane = threadIdx.x & 63;
  int hid = blockIdx.x * 4 + wave;
  int t = hid / 20;
  int sub = hid - t * 20;
  int n = t & (N_ - 1);
  bf16* ptr;
  float oscale;
  if (sub < 16) {
    ptr = q + ((size_t)t * 16 + sub) * 64;
    oscale = QSCALE;
  } else {
    ptr = kv + (size_t)t * 512 + (sub - 16) * 64;
    oscale = 1.0f;
  }
  float x = (float)ptr[lane];
  float ss = x * x;
  ss += __shfl_xor(ss, 1);
  ss += __shfl_xor(ss, 2);
  ss += __shfl_xor(ss, 4);
  ss += __shfl_xor(ss, 8);
  ss += __shfl_xor(ss, 16);
  ss += __shfl_xor(ss, 32);
  float rn = rsqrtf(ss * (1.0f / 64.0f) + 1.1920929e-07f);
  float xn = x * rn;
  float pr = __shfl_xor(xn, 32);
  float rot = (lane < 32) ? -pr : pr;
  float ang = (float)n * exp2f(-0.41524101186092029f * (float)(lane & 31));
  float sv, cv;
  sincosf(ang, &sv, &cv);
  ptr[lane] = (bf16)((xn * cv + rot * sv) * oscale);
}

// ---------------------------------------------------------------------------
// Causal flash attention with GQA — TRANSPOSED dataflow (S^T / O^T),
// PERSISTENT work-queue version (unchanged from round 3; counters showed
// it dropped below the GEMMs).
__global__ __launch_bounds__(256) void attn(bf16* __restrict__ q,
                                            const bf16* __restrict__ kv,
                                            const bf16* __restrict__ vt) {
  __shared__ __align__(16) bf16 Ks[64 * 72];  // [key][d]
  __shared__ __align__(16) bf16 Vs[64 * 72];  // [d][key]
  __shared__ __align__(16) bf16 Ps[64 * 72];  // [q-row][key], wave-private rows
  __shared__ int s_item;
  int tid = threadIdx.x;
  int wave = tid >> 6, lane = tid & 63;
  int quad = lane >> 4, lr = lane & 15;
  int srow = tid >> 3, soff = (tid & 7) * 8;
  const f32x4 z = {0.f, 0.f, 0.f, 0.f};

  while (true) {
    if (tid == 0) s_item = atomicAdd(&g_ctr, 1);
    __syncthreads();  // publish s_item; also: all waves done with prev item's LDS
    int item = s_item;
    if (item >= 2048) break;
    int j = 31 - (item >> 6);  // 64-row q-tile index, longest first
    int rr = item & 63;
    int b = rr & 3, h = rr >> 2, hkv = h >> 2;
    int qrow0 = j * 64 + wave * 16;  // this wave's first q-row
    int nkt = j + 1;

    // Q fragments (B-operand = Q^T): lane holds Q[qrow0+lr][kx*32+quad*8..]
    bf16x8 qf[2];
#pragma unroll
    for (int kx = 0; kx < 2; ++kx)
      qf[kx] = *(const bf16x8*)(
          q + ((size_t)(b * N_ + qrow0 + lr) * H_ + h) * D_ + kx * 32 + quad * 8);

    f32x4 acc[4];  // acc[dt] = O^T tile: row d=dt*16+quad*4+r, col qrow=lr
    float m_i = NEGINF, l_i = 0.f;
#pragma unroll
    for (int dt = 0; dt < 4; ++dt) acc[dt] = z;

    // ---- prologue: stage tile 0 synchronously
    bf16x8 sk0, sk1, sv0, sv1;
    sk0 = *(const bf16x8*)(kv + (size_t)(b * N_ + srow) * 512 + hkv * 64 + soff);
    sk1 = *(const bf16x8*)(kv + (size_t)(b * N_ + srow + 32) * 512 + hkv * 64 + soff);
    sv0 = *(const bf16x8*)(vt + ((size_t)(b * HKV_ + hkv) * 64 + srow) * N_ + soff);
    sv1 = *(const bf16x8*)(vt + ((size_t)(b * HKV_ + hkv) * 64 + srow + 32) * N_ + soff);
    *(bf16x8*)(Ks + srow * 72 + soff) = sk0;
    *(bf16x8*)(Ks + (srow + 32) * 72 + soff) = sk1;
    *(bf16x8*)(Vs + srow * 72 + soff) = sv0;
    *(bf16x8*)(Vs + (srow + 32) * 72 + soff) = sv1;
    asm volatile("s_waitcnt lgkmcnt(0)" ::: "memory");
    __builtin_amdgcn_s_barrier();
    __builtin_amdgcn_sched_barrier(0);

    for (int kt = 0; kt < nkt; ++kt) {
      // ---- issue NEXT tile's global loads early (in flight across compute)
      bool pf = (kt + 1 < nkt);
      if (pf) {
        int krow = (kt + 1) * 64;
        sk0 = *(const bf16x8*)(kv + (size_t)(b * N_ + krow + srow) * 512 + hkv * 64 + soff);
        sk1 = *(const bf16x8*)(kv + (size_t)(b * N_ + krow + srow + 32) * 512 + hkv * 64 + soff);
        sv0 = *(const bf16x8*)(vt + ((size_t)(b * HKV_ + hkv) * 64 + srow) * N_ + krow + soff);
        sv1 = *(const bf16x8*)(vt + ((size_t)(b * HKV_ + hkv) * 64 + srow + 32) * N_ + krow + soff);
      }

      // S^T = K·Q^T: st[ct] — key = kt*64 + ct*16 + quad*4 + r, qrow col = lr
      f32x4 st[4];
#pragma unroll
      for (int ct = 0; ct < 4; ++ct) st[ct] = z;
#pragma unroll
      for (int kx = 0; kx < 2; ++kx) {
        bf16x8 kf[4];
#pragma unroll
        for (int ct = 0; ct < 4; ++ct)
          kf[ct] = *(const bf16x8*)(Ks + (ct * 16 + lr) * 72 + kx * 32 + quad * 8);
        __builtin_amdgcn_s_setprio(1);
#pragma unroll
        for (int ct = 0; ct < 4; ++ct)
          st[ct] = __builtin_amdgcn_mfma_f32_16x16x32_bf16(kf[ct], qf[kx], st[ct], 0, 0, 0);
        __builtin_amdgcn_s_setprio(0);
      }
      // Causal mask — only the diagonal tile kt == j crosses the diagonal
      if (kt == j) {
        int qrow = qrow0 + lr;
#pragma unroll
        for (int ct = 0; ct < 4; ++ct)
#pragma unroll
          for (int r = 0; r < 4; ++r) {
            int key = kt * 64 + ct * 16 + quad * 4 + r;
            if (key > qrow) st[ct][r] = NEGINF;
          }
      }
      // Online softmax: per-lane scalar state, 2+2 shuffles
      float mx = NEGINF;
#pragma unroll
      for (int ct = 0; ct < 4; ++ct)
#pragma unroll
        for (int r = 0; r < 4; ++r) mx = fmaxf(mx, st[ct][r]);
      mx = fmaxf(mx, __shfl_xor(mx, 16));
      mx = fmaxf(mx, __shfl_xor(mx, 32));
      float mnew = fmaxf(m_i, mx);
      float alpha = exp2f(m_i - mnew);
      m_i = mnew;
      float rs = 0.f;
#pragma unroll
      for (int ct = 0; ct < 4; ++ct)
#pragma unroll
        for (int r = 0; r < 4; ++r) {
          float p = exp2f(st[ct][r] - mnew);
          st[ct][r] = p;
          rs += p;
        }
      rs += __shfl_xor(rs, 16);
      rs += __shfl_xor(rs, 32);
      l_i = l_i * alpha + rs;
#pragma unroll
      for (int dt = 0; dt < 4; ++dt)
#pragma unroll
        for (int r = 0; r < 4; ++r) acc[dt][r] *= alpha;
      // P^T -> Ps[qrow][key]: b64 vector writes (keys quad*4+r contiguous)
#pragma unroll
      for (int ct = 0; ct < 4; ++ct) {
        bf16x4 pk;
#pragma unroll
        for (int r = 0; r < 4; ++r) pk[r] = (bf16)st[ct][r];
        *(bf16x4*)(Ps + (wave * 16 + lr) * 72 + ct * 16 + quad * 4) = pk;
      }
      // Wave-local LDS ordering (rows wave-private, guard wave-uniform)
      asm volatile("s_waitcnt lgkmcnt(0)" ::: "memory");
      // O^T += V^T·P^T
#pragma unroll
      for (int kx = 0; kx < 2; ++kx) {
        bf16x8 vf[4], pfr;
#pragma unroll
        for (int dt = 0; dt < 4; ++dt)
          vf[dt] = *(const bf16x8*)(Vs + (dt * 16 + lr) * 72 + kx * 32 + quad * 8);
        pfr = *(const bf16x8*)(Ps + (wave * 16 + lr) * 72 + kx * 32 + quad * 8);
        __builtin_amdgcn_s_setprio(1);
#pragma unroll
        for (int dt = 0; dt < 4; ++dt)
          acc[dt] = __builtin_amdgcn_mfma_f32_16x16x32_bf16(vf[dt], pfr, acc[dt], 0, 0, 0);
        __builtin_amdgcn_s_setprio(0);
      }

      // ---- all waves done READING tile kt; prefetch loads stay in flight
      __builtin_amdgcn_s_barrier();
      __builtin_amdgcn_sched_barrier(0);
      if (pf) {
        // compiler inserts s_waitcnt vmcnt(0) before first use of sk*/sv*
        *(bf16x8*)(Ks + srow * 72 + soff) = sk0;
        *(bf16x8*)(Ks + (srow + 32) * 72 + soff) = sk1;
        *(bf16x8*)(Vs + srow * 72 + soff) = sv0;
        *(bf16x8*)(Vs + (srow + 32) * 72 + soff) = sv1;
        asm volatile("s_waitcnt lgkmcnt(0)" ::: "memory");
      }
      __builtin_amdgcn_s_barrier();  // tile kt+1 visible to all waves
      __builtin_amdgcn_sched_barrier(0);
    }

    // Epilogue: y = O / l — lane owns q-row lr, d = dt*16+quad*4+r
    float inv = 1.0f / l_i;
    int qrow = qrow0 + lr;
#pragma unroll
    for (int dt = 0; dt < 4; ++dt) {
      bf16x4 ov;
#pragma unroll
      for (int r = 0; r < 4; ++r) ov[r] = (bf16)(acc[dt][r] * inv);
      *(bf16x4*)(q + ((size_t)(b * N_ + qrow) * H_ + h) * D_ + dt * 16 + quad * 4) = ov;
    }
  }
}

// ---------------------------------------------------------------------------
extern "C" void kernel_launch(void* const* d_in, const int* in_sizes, int n_in,
                              void* d_out, int out_size, void* d_ws, size_t ws_size,
                              hipStream_t stream) {
  // Inputs FP32; output FP32. Intermediates bf16.
  const float* x = (const float*)d_in[0];
  const float* wq = (const float*)d_in[1];
  const float* wk = (const float*)d_in[2];
  const float* wv = (const float*)d_in[3];
  const float* wo = (const float*)d_in[4];
  float* out = (float*)d_out;
  char* ws = (char*)d_ws;
  // ws (28 MB): q/y 16 MB [0,16M) | kv 8 MB [16M,24M) | region [24M,28M) is
  // time-shared: wqkvT (3 MB, dead after gemm_qkv) -> vt (4 MB, dead after
  // attn) -> woT (2 MB). Stream ordering makes the aliasing safe.
  bf16* q = (bf16*)(ws);
  bf16* kv = (bf16*)(ws + 16777216);
  bf16* vt = (bf16*)(ws + 25165824);
  bf16* wqkvT = (bf16*)(ws + 25165824);
  bf16* woT = (bf16*)(ws + 25165824);

  prep_qkv<<<dim3(384), 256, 0, stream>>>(wq, wk, wv, wqkvT);
  gemm_qkv<<<dim3(64, 12), 256, 0, stream>>>(x, wqkvT, q, kv);
  norm_rope<<<dim3(40960), 256, 0, stream>>>(q, kv);
  transpose_v<<<dim3(32, 16), 256, 0, stream>>>(kv, vt);
  attn<<<dim3(1280), 256, 0, stream>>>(q, kv, vt);
  prep_wo<<<dim3(256), 256, 0, stream>>>(wo, woT);
  gemm_out<<<dim3(64, 8), 256, 0, stream>>>(q, woT, out);
}

// Round 6
// 287.978 us; speedup vs baseline: 2.0536x; 1.0387x over previous
//
#include <hip/hip_runtime.h>

typedef __bf16 bf16;
typedef __bf16 bf16x8 __attribute__((ext_vector_type(8)));
typedef __bf16 bf16x4 __attribute__((ext_vector_type(4)));
typedef float f32x4 __attribute__((ext_vector_type(4)));

#define B_ 4
#define N_ 2048
#define C_ 1024
#define H_ 16
#define HKV_ 4
#define D_ 64

// fold: 1.5 (qk_gain) * 0.125 (1/sqrt(64)) * log2(e)  -> use exp2f in softmax
#define QSCALE 0.2705053201666806f
#define NEGINF (-1.0e30f)

// work queue for persistent attn (reset by transpose_v each launch)
__device__ int g_ctr;

// ---------------------------------------------------------------------------
// Weight prep: w [1024 k][ncols n] f32 -> wT [n][1024 k] bf16 (+ convert).
__global__ __launch_bounds__(256) void prep_qkv(const float* __restrict__ wq,
                                                const float* __restrict__ wk,
                                                const float* __restrict__ wv,
                                                bf16* __restrict__ wT) {
  __shared__ __align__(16) bf16 lds[64 * 72];
  int bx = blockIdx.x;
  const float* w;
  int ncols, tk, tn, nbase;
  if (bx < 256) {
    w = wq; ncols = 1024; tk = bx >> 4; tn = bx & 15; nbase = 0;
  } else if (bx < 320) {
    int t = bx - 256;
    w = wk; ncols = 256; tk = t >> 2; tn = t & 3; nbase = 1024;
  } else {
    int t = bx - 320;
    w = wv; ncols = 256; tk = t >> 2; tn = t & 3; nbase = 1280;
  }
  int tid = threadIdx.x;
#pragma unroll
  for (int i = 0; i < 4; ++i) {
    int c = tid + i * 256;
    int kr = c >> 4, n4 = (c & 15) * 4;
    f32x4 v = *(const f32x4*)(w + (size_t)(tk * 64 + kr) * ncols + tn * 64 + n4);
    bf16x4 b;
#pragma unroll
    for (int j = 0; j < 4; ++j) b[j] = (bf16)v[j];
    *(bf16x4*)(lds + kr * 72 + n4) = b;
  }
  __syncthreads();
#pragma unroll
  for (int i = 0; i < 2; ++i) {
    int c = tid + i * 256;
    int n = c >> 3, koff = (c & 7) * 8;
    bf16x8 tv;
#pragma unroll
    for (int j = 0; j < 8; ++j) tv[j] = lds[(koff + j) * 72 + n];
    *(bf16x8*)(wT + (size_t)(nbase + tn * 64 + n) * 1024 + tk * 64 + koff) = tv;
  }
}

// Single-matrix variant for wo (1024x1024), launched after attn (aliases vt).
__global__ __launch_bounds__(256) void prep_wo(const float* __restrict__ w,
                                               bf16* __restrict__ wT) {
  __shared__ __align__(16) bf16 lds[64 * 72];
  int tk = blockIdx.x >> 4, tn = blockIdx.x & 15;
  int tid = threadIdx.x;
#pragma unroll
  for (int i = 0; i < 4; ++i) {
    int c = tid + i * 256;
    int kr = c >> 4, n4 = (c & 15) * 4;
    f32x4 v = *(const f32x4*)(w + (size_t)(tk * 64 + kr) * 1024 + tn * 64 + n4);
    bf16x4 b;
#pragma unroll
    for (int j = 0; j < 4; ++j) b[j] = (bf16)v[j];
    *(bf16x4*)(lds + kr * 72 + n4) = b;
  }
  __syncthreads();
#pragma unroll
  for (int i = 0; i < 2; ++i) {
    int c = tid + i * 256;
    int n = c >> 3, koff = (c & 7) * 8;
    bf16x8 tv;
#pragma unroll
    for (int j = 0; j < 8; ++j) tv[j] = lds[(koff + j) * 72 + n];
    *(bf16x8*)(wT + (size_t)(tn * 64 + n) * 1024 + tk * 64 + koff) = tv;
  }
}

// ---------------------------------------------------------------------------
// Fused QKV projection, bf16 pre-transposed weights. Grid (64, 12).
__global__ __launch_bounds__(256) void gemm_qkv(const float* __restrict__ x,
                                                const bf16* __restrict__ wT,
                                                bf16* __restrict__ qb,
                                                bf16* __restrict__ kvb) {
  __shared__ __align__(16) bf16 As[128 * 72];
  __shared__ __align__(16) bf16 Bs[128 * 72];
  int by = blockIdx.y;
  int n0 = by * 128;  // row into wT[1536][1024]
  bf16* Out;
  int ostride, ocol0;
  if (by < 8) {
    Out = qb; ostride = 1024; ocol0 = by * 128;
  } else if (by < 10) {
    Out = kvb; ostride = 512; ocol0 = (by - 8) * 128;
  } else {
    Out = kvb; ostride = 512; ocol0 = 256 + (by - 10) * 128;
  }
  int m0 = blockIdx.x * 128;
  int tid = threadIdx.x;
  int wave = tid >> 6, lane = tid & 63;
  int quad = lane >> 4, lr = lane & 15;
  int wr = (wave >> 1) * 64, wc = (wave & 1) * 64;

  f32x4 acc[4][4];
  const f32x4 z = {0.f, 0.f, 0.f, 0.f};
#pragma unroll
  for (int i = 0; i < 4; ++i)
#pragma unroll
    for (int j = 0; j < 4; ++j) acc[i][j] = z;

  for (int k0 = 0; k0 < 1024; k0 += 64) {
    __syncthreads();
#pragma unroll
    for (int i = 0; i < 8; ++i) {
      int c = tid + i * 256;
      int row = c >> 4, off4 = (c & 15) * 4;
      f32x4 av = *(const f32x4*)(x + (size_t)(m0 + row) * 1024 + k0 + off4);
      bf16x4 a16;
#pragma unroll
      for (int j = 0; j < 4; ++j) a16[j] = (bf16)av[j];
      *(bf16x4*)(As + row * 72 + off4) = a16;
    }
#pragma unroll
    for (int i = 0; i < 4; ++i) {
      int c = tid + i * 256;
      int row = c >> 3, off = (c & 7) * 8;
      *(bf16x8*)(Bs + row * 72 + off) =
          *(const bf16x8*)(wT + (size_t)(n0 + row) * 1024 + k0 + off);
    }
    __syncthreads();
#pragma unroll
    for (int kx = 0; kx < 2; ++kx) {
      bf16x8 af[4], bfr[4];
#pragma unroll
      for (int t = 0; t < 4; ++t) {
        af[t] = *(const bf16x8*)(As + (wr + t * 16 + lr) * 72 + kx * 32 + quad * 8);
        bfr[t] = *(const bf16x8*)(Bs + (wc + t * 16 + lr) * 72 + kx * 32 + quad * 8);
      }
#pragma unroll
      for (int rt = 0; rt < 4; ++rt)
#pragma unroll
        for (int ct = 0; ct < 4; ++ct)
          acc[rt][ct] = __builtin_amdgcn_mfma_f32_16x16x32_bf16(af[rt], bfr[ct],
                                                                acc[rt][ct], 0, 0, 0);
    }
  }
#pragma unroll
  for (int rt = 0; rt < 4; ++rt)
#pragma unroll
    for (int ct = 0; ct < 4; ++ct)
#pragma unroll
      for (int r = 0; r < 4; ++r) {
        int row = m0 + wr + rt * 16 + quad * 4 + r;
        int col = ocol0 + wc + ct * 16 + lr;
        Out[(size_t)row * ostride + col] = (bf16)acc[rt][ct][r];
      }
}

// ---------------------------------------------------------------------------
// Output projection: A = attn output (bf16), B^T = woT bf16, C = float out.
__global__ __launch_bounds__(256) void gemm_out(const bf16* __restrict__ A,
                                                const bf16* __restrict__ Bt,
                                                float* __restrict__ C) {
  __shared__ __align__(16) bf16 As[128 * 72];
  __shared__ __align__(16) bf16 Bs[128 * 72];
  int m0 = blockIdx.x * 128, n0 = blockIdx.y * 128;
  int tid = threadIdx.x;
  int wave = tid >> 6, lane = tid & 63;
  int quad = lane >> 4, lr = lane & 15;
  int wr = (wave >> 1) * 64, wc = (wave & 1) * 64;

  f32x4 acc[4][4];
  const f32x4 z = {0.f, 0.f, 0.f, 0.f};
#pragma unroll
  for (int i = 0; i < 4; ++i)
#pragma unroll
    for (int j = 0; j < 4; ++j) acc[i][j] = z;

  for (int k0 = 0; k0 < 1024; k0 += 64) {
    __syncthreads();
#pragma unroll
    for (int i = 0; i < 4; ++i) {
      int c = tid + i * 256;
      int row = c >> 3, off = (c & 7) * 8;
      *(bf16x8*)(As + row * 72 + off) =
          *(const bf16x8*)(A + (size_t)(m0 + row) * 1024 + k0 + off);
      *(bf16x8*)(Bs + row * 72 + off) =
          *(const bf16x8*)(Bt + (size_t)(n0 + row) * 1024 + k0 + off);
    }
    __syncthreads();
#pragma unroll
    for (int kx = 0; kx < 2; ++kx) {
      bf16x8 af[4], bfr[4];
#pragma unroll
      for (int t = 0; t < 4; ++t) {
        af[t] = *(const bf16x8*)(As + (wr + t * 16 + lr) * 72 + kx * 32 + quad * 8);
        bfr[t] = *(const bf16x8*)(Bs + (wc + t * 16 + lr) * 72 + kx * 32 + quad * 8);
      }
#pragma unroll
      for (int rt = 0; rt < 4; ++rt)
#pragma unroll
        for (int ct = 0; ct < 4; ++ct)
          acc[rt][ct] = __builtin_amdgcn_mfma_f32_16x16x32_bf16(af[rt], bfr[ct],
                                                                acc[rt][ct], 0, 0, 0);
    }
  }
#pragma unroll
  for (int rt = 0; rt < 4; ++rt)
#pragma unroll
    for (int ct = 0; ct < 4; ++ct)
#pragma unroll
      for (int r = 0; r < 4; ++r) {
        int row = m0 + wr + rt * 16 + quad * 4 + r;
        int col = n0 + wc + ct * 16 + lr;
        C[(size_t)row * 1024 + col] = acc[rt][ct][r];
      }
}

// ---------------------------------------------------------------------------
// V transpose: kv [B*N][512] -> vt [B][HKV][D][N].  Also resets work queue.
__global__ __launch_bounds__(256) void transpose_v(const bf16* __restrict__ kv,
                                                   bf16* __restrict__ vt) {
  __shared__ __align__(16) bf16 lds[64 * 72];
  if (blockIdx.x == 0 && blockIdx.y == 0 && threadIdx.x == 0) g_ctr = 0;
  int nt = blockIdx.x;
  int bh = blockIdx.y;
  int b = bh >> 2, hkv = bh & 3;
  int tid = threadIdx.x;
#pragma unroll
  for (int i = 0; i < 2; ++i) {
    int c = tid + i * 256;
    int tok = c >> 3, off = (c & 7) * 8;
    *(bf16x8*)(lds + tok * 72 + off) =
        *(const bf16x8*)(kv + (size_t)(b * N_ + nt * 64 + tok) * 512 + 256 + hkv * 64 + off);
  }
  __syncthreads();
#pragma unroll
  for (int i = 0; i < 2; ++i) {
    int c = tid + i * 256;
    int d = c >> 3, toff = (c & 7) * 8;
    bf16x8 tv;
#pragma unroll
    for (int j = 0; j < 8; ++j) tv[j] = lds[(toff + j) * 72 + d];
    *(bf16x8*)(vt + ((size_t)bh * 64 + d) * N_ + nt * 64 + toff) = tv;
  }
}

// ---------------------------------------------------------------------------
// Per-head RMSNorm + RoPE, in place. __sincosf (v_sin/v_cos path) instead of
// libm sincosf: err ~1e-4 rad at ang<=2047 << bf16 quantization (3.9e-3).
__global__ __launch_bounds__(256) void norm_rope(bf16* __restrict__ q,
                                                 bf16* __restrict__ kv) {
  int wave = threadIdx.x >> 6, lane = threadIdx.x & 63;
  int hid = blockIdx.x * 4 + wave;
  int t = hid / 20;
  int sub = hid - t * 20;
  int n = t & (N_ - 1);
  bf16* ptr;
  float oscale;
  if (sub < 16) {
    ptr = q + ((size_t)t * 16 + sub) * 64;
    oscale = QSCALE;
  } else {
    ptr = kv + (size_t)t * 512 + (sub - 16) * 64;
    oscale = 1.0f;
  }
  float x = (float)ptr[lane];
  float ss = x * x;
  ss += __shfl_xor(ss, 1);
  ss += __shfl_xor(ss, 2);
  ss += __shfl_xor(ss, 4);
  ss += __shfl_xor(ss, 8);
  ss += __shfl_xor(ss, 16);
  ss += __shfl_xor(ss, 32);
  float rn = rsqrtf(ss * (1.0f / 64.0f) + 1.1920929e-07f);
  float xn = x * rn;
  float pr = __shfl_xor(xn, 32);
  float rot = (lane < 32) ? -pr : pr;
  float ang = (float)n * exp2f(-0.41524101186092029f * (float)(lane & 31));
  float sv, cv;
  __sincosf(ang, &sv, &cv);
  ptr[lane] = (bf16)((xn * cv + rot * sv) * oscale);
}

// ---------------------------------------------------------------------------
// Causal flash attention with GQA — TRANSPOSED dataflow (S^T / O^T),
// persistent work-queue. Round-4 changes (resubmitted after infra failure):
//   1. T2 XOR-swizzle: Ks/Vs/Ps are [64][64] linear (no pad); 16B-unit index
//      is XORed with (row&7) on BOTH write and read. Kills the 8-way b128
//      read conflicts the 72-pad left behind (11.9M conflict cycles).
//   2. T13 defer-max: skip the acc/l rescale when no row's max grew by >8
//      (exp2-domain). After tile 0 this skips nearly always.
//   3. Prefetch pointers strength-reduced (kp += 64*512, vp += 64).
//   LDS 24.6 KB -> 6 blocks/CU; grid 1536.
__global__ __launch_bounds__(256) void attn(bf16* __restrict__ q,
                                            const bf16* __restrict__ kv,
                                            const bf16* __restrict__ vt) {
  __shared__ __align__(16) bf16 Ks[64 * 64];  // [key][d], swizzled
  __shared__ __align__(16) bf16 Vs[64 * 64];  // [d][key], swizzled
  __shared__ __align__(16) bf16 Ps[64 * 64];  // [q-row][key], swizzled
  __shared__ int s_item;
  int tid = threadIdx.x;
  int wave = tid >> 6, lane = tid & 63;
  int quad = lane >> 4, lr = lane & 15;
  int srow = tid >> 3, soff = (tid & 7) * 8;
  int su = ((tid & 7) ^ (srow & 7)) * 8;  // swizzled LDS unit (same for srow+32)
  int e7 = lr & 7;                        // read-side row XOR key
  const f32x4 z = {0.f, 0.f, 0.f, 0.f};

  while (true) {
    if (tid == 0) s_item = atomicAdd(&g_ctr, 1);
    __syncthreads();  // publish s_item; also: all waves done with prev item's LDS
    int item = s_item;
    if (item >= 2048) break;
    int j = 31 - (item >> 6);  // 64-row q-tile index, longest first
    int rr = item & 63;
    int b = rr & 3, h = rr >> 2, hkv = h >> 2;
    int qrow0 = j * 64 + wave * 16;  // this wave's first q-row
    int nkt = j + 1;

    // Q fragments (B-operand = Q^T): lane holds Q[qrow0+lr][kx*32+quad*8..]
    bf16x8 qf[2];
#pragma unroll
    for (int kx = 0; kx < 2; ++kx)
      qf[kx] = *(const bf16x8*)(
          q + ((size_t)(b * N_ + qrow0 + lr) * H_ + h) * D_ + kx * 32 + quad * 8);

    f32x4 acc[4];  // acc[dt] = O^T tile: row d=dt*16+quad*4+r, col qrow=lr
    float m_i = NEGINF, l_i = 0.f;
#pragma unroll
    for (int dt = 0; dt < 4; ++dt) acc[dt] = z;

    // staging pointers (strength-reduced; advance per tile)
    const bf16* kp = kv + (size_t)(b * N_ + srow) * 512 + hkv * 64 + soff;
    const bf16* vp = vt + ((size_t)(b * HKV_ + hkv) * 64 + srow) * N_ + soff;

    // ---- prologue: stage tile 0 synchronously
    bf16x8 sk0, sk1, sv0, sv1;
    sk0 = *(const bf16x8*)(kp);
    sk1 = *(const bf16x8*)(kp + 32 * 512);
    sv0 = *(const bf16x8*)(vp);
    sv1 = *(const bf16x8*)(vp + 32 * N_);
    *(bf16x8*)(Ks + srow * 64 + su) = sk0;
    *(bf16x8*)(Ks + (srow + 32) * 64 + su) = sk1;
    *(bf16x8*)(Vs + srow * 64 + su) = sv0;
    *(bf16x8*)(Vs + (srow + 32) * 64 + su) = sv1;
    asm volatile("s_waitcnt lgkmcnt(0)" ::: "memory");
    __builtin_amdgcn_s_barrier();
    __builtin_amdgcn_sched_barrier(0);

    for (int kt = 0; kt < nkt; ++kt) {
      // ---- issue NEXT tile's global loads early (in flight across compute)
      bool pf = (kt + 1 < nkt);
      if (pf) {
        kp += 64 * 512;
        vp += 64;
        sk0 = *(const bf16x8*)(kp);
        sk1 = *(const bf16x8*)(kp + 32 * 512);
        sv0 = *(const bf16x8*)(vp);
        sv1 = *(const bf16x8*)(vp + 32 * N_);
      }

      // S^T = K·Q^T: st[ct] — key = kt*64 + ct*16 + quad*4 + r, qrow col = lr
      f32x4 st[4];
#pragma unroll
      for (int ct = 0; ct < 4; ++ct) st[ct] = z;
#pragma unroll
      for (int kx = 0; kx < 2; ++kx) {
        bf16x8 kf[4];
#pragma unroll
        for (int ct = 0; ct < 4; ++ct)
          kf[ct] = *(const bf16x8*)(Ks + (ct * 16 + lr) * 64 + (((kx * 4 + quad) ^ e7) * 8));
        __builtin_amdgcn_s_setprio(1);
#pragma unroll
        for (int ct = 0; ct < 4; ++ct)
          st[ct] = __builtin_amdgcn_mfma_f32_16x16x32_bf16(kf[ct], qf[kx], st[ct], 0, 0, 0);
        __builtin_amdgcn_s_setprio(0);
      }
      // Causal mask — only the diagonal tile kt == j crosses the diagonal
      if (kt == j) {
        int qrow = qrow0 + lr;
#pragma unroll
        for (int ct = 0; ct < 4; ++ct)
#pragma unroll
          for (int r = 0; r < 4; ++r) {
            int key = kt * 64 + ct * 16 + quad * 4 + r;
            if (key > qrow) st[ct][r] = NEGINF;
          }
      }
      // Online softmax with defer-max (T13): rescale only on >8 max growth.
      float mx = NEGINF;
#pragma unroll
      for (int ct = 0; ct < 4; ++ct)
#pragma unroll
        for (int r = 0; r < 4; ++r) mx = fmaxf(mx, st[ct][r]);
      mx = fmaxf(mx, __shfl_xor(mx, 16));
      mx = fmaxf(mx, __shfl_xor(mx, 32));
      if (__any(mx > m_i + 8.0f)) {
        float mnew = fmaxf(m_i, mx);
        float alpha = exp2f(m_i - mnew);
        m_i = mnew;
        l_i *= alpha;
#pragma unroll
        for (int dt = 0; dt < 4; ++dt)
#pragma unroll
          for (int r = 0; r < 4; ++r) acc[dt][r] *= alpha;
      }
      float rs = 0.f;
#pragma unroll
      for (int ct = 0; ct < 4; ++ct)
#pragma unroll
        for (int r = 0; r < 4; ++r) {
          float p = exp2f(st[ct][r] - m_i);
          st[ct][r] = p;
          rs += p;
        }
      rs += __shfl_xor(rs, 16);
      rs += __shfl_xor(rs, 32);
      l_i += rs;
      // P^T -> Ps[qrow][key] (swizzled): b64 writes, keys quad*4+r contiguous
#pragma unroll
      for (int ct = 0; ct < 4; ++ct) {
        bf16x4 pk;
#pragma unroll
        for (int r = 0; r < 4; ++r) pk[r] = (bf16)st[ct][r];
        int pu = (((ct * 2) + (quad >> 1)) ^ e7) * 8 + (quad & 1) * 4;
        *(bf16x4*)(Ps + (wave * 16 + lr) * 64 + pu) = pk;
      }
      // Wave-local LDS ordering (rows wave-private, guard wave-uniform)
      asm volatile("s_waitcnt lgkmcnt(0)" ::: "memory");
      // O^T += V^T·P^T
#pragma unroll
      for (int kx = 0; kx < 2; ++kx) {
        bf16x8 vf[4], pfr;
#pragma unroll
        for (int dt = 0; dt < 4; ++dt)
          vf[dt] = *(const bf16x8*)(Vs + (dt * 16 + lr) * 64 + (((kx * 4 + quad) ^ e7) * 8));
        pfr = *(const bf16x8*)(Ps + (wave * 16 + lr) * 64 + (((kx * 4 + quad) ^ e7) * 8));
        __builtin_amdgcn_s_setprio(1);
#pragma unroll
        for (int dt = 0; dt < 4; ++dt)
          acc[dt] = __builtin_amdgcn_mfma_f32_16x16x32_bf16(vf[dt], pfr, acc[dt], 0, 0, 0);
        __builtin_amdgcn_s_setprio(0);
      }

      // ---- all waves done READING tile kt; prefetch loads stay in flight
      __builtin_amdgcn_s_barrier();
      __builtin_amdgcn_sched_barrier(0);
      if (pf) {
        // compiler inserts s_waitcnt vmcnt(0) before first use of sk*/sv*
        *(bf16x8*)(Ks + srow * 64 + su) = sk0;
        *(bf16x8*)(Ks + (srow + 32) * 64 + su) = sk1;
        *(bf16x8*)(Vs + srow * 64 + su) = sv0;
        *(bf16x8*)(Vs + (srow + 32) * 64 + su) = sv1;
        asm volatile("s_waitcnt lgkmcnt(0)" ::: "memory");
      }
      __builtin_amdgcn_s_barrier();  // tile kt+1 visible to all waves
      __builtin_amdgcn_sched_barrier(0);
    }

    // Epilogue: y = O / l — lane owns q-row lr, d = dt*16+quad*4+r
    float inv = 1.0f / l_i;
    int qrow = qrow0 + lr;
#pragma unroll
    for (int dt = 0; dt < 4; ++dt) {
      bf16x4 ov;
#pragma unroll
      for (int r = 0; r < 4; ++r) ov[r] = (bf16)(acc[dt][r] * inv);
      *(bf16x4*)(q + ((size_t)(b * N_ + qrow) * H_ + h) * D_ + dt * 16 + quad * 4) = ov;
    }
  }
}

// ---------------------------------------------------------------------------
extern "C" void kernel_launch(void* const* d_in, const int* in_sizes, int n_in,
                              void* d_out, int out_size, void* d_ws, size_t ws_size,
                              hipStream_t stream) {
  // Inputs FP32; output FP32. Intermediates bf16.
  const float* x = (const float*)d_in[0];
  const float* wq = (const float*)d_in[1];
  const float* wk = (const float*)d_in[2];
  const float* wv = (const float*)d_in[3];
  const float* wo = (const float*)d_in[4];
  float* out = (float*)d_out;
  char* ws = (char*)d_ws;
  // ws (28 MB): q/y 16 MB [0,16M) | kv 8 MB [16M,24M) | region [24M,28M) is
  // time-shared: wqkvT (3 MB) -> vt (4 MB) -> woT (2 MB).
  bf16* q = (bf16*)(ws);
  bf16* kv = (bf16*)(ws + 16777216);
  bf16* vt = (bf16*)(ws + 25165824);
  bf16* wqkvT = (bf16*)(ws + 25165824);
  bf16* woT = (bf16*)(ws + 25165824);

  prep_qkv<<<dim3(384), 256, 0, stream>>>(wq, wk, wv, wqkvT);
  gemm_qkv<<<dim3(64, 12), 256, 0, stream>>>(x, wqkvT, q, kv);
  norm_rope<<<dim3(40960), 256, 0, stream>>>(q, kv);
  transpose_v<<<dim3(32, 16), 256, 0, stream>>>(kv, vt);
  attn<<<dim3(1536), 256, 0, stream>>>(q, kv, vt);
  prep_wo<<<dim3(256), 256, 0, stream>>>(wo, woT);
  gemm_out<<<dim3(64, 8), 256, 0, stream>>>(q, woT, out);
}

// Round 7
// 265.366 us; speedup vs baseline: 2.2286x; 1.0852x over previous
//
#include <hip/hip_runtime.h>

typedef __bf16 bf16;
typedef __bf16 bf16x8 __attribute__((ext_vector_type(8)));
typedef __bf16 bf16x4 __attribute__((ext_vector_type(4)));
typedef float f32x4 __attribute__((ext_vector_type(4)));

#define B_ 4
#define N_ 2048
#define C_ 1024
#define H_ 16
#define HKV_ 4
#define D_ 64

// fold: 1.5 (qk_gain) * 0.125 (1/sqrt(64)) * log2(e)  -> use exp2f in softmax
#define QSCALE 0.2705053201666806f
#define NEGINF (-1.0e30f)

// work queue for persistent attn (reset by transpose_v each launch)
__device__ int g_ctr;

// ---------------------------------------------------------------------------
// Weight prep: w [1024 k][ncols n] f32 -> wT [n][1024 k] bf16 (+ convert).
__global__ __launch_bounds__(256) void prep_qkv(const float* __restrict__ wq,
                                                const float* __restrict__ wk,
                                                const float* __restrict__ wv,
                                                bf16* __restrict__ wT) {
  __shared__ __align__(16) bf16 lds[64 * 72];
  int bx = blockIdx.x;
  const float* w;
  int ncols, tk, tn, nbase;
  if (bx < 256) {
    w = wq; ncols = 1024; tk = bx >> 4; tn = bx & 15; nbase = 0;
  } else if (bx < 320) {
    int t = bx - 256;
    w = wk; ncols = 256; tk = t >> 2; tn = t & 3; nbase = 1024;
  } else {
    int t = bx - 320;
    w = wv; ncols = 256; tk = t >> 2; tn = t & 3; nbase = 1280;
  }
  int tid = threadIdx.x;
#pragma unroll
  for (int i = 0; i < 4; ++i) {
    int c = tid + i * 256;
    int kr = c >> 4, n4 = (c & 15) * 4;
    f32x4 v = *(const f32x4*)(w + (size_t)(tk * 64 + kr) * ncols + tn * 64 + n4);
    bf16x4 b;
#pragma unroll
    for (int j = 0; j < 4; ++j) b[j] = (bf16)v[j];
    *(bf16x4*)(lds + kr * 72 + n4) = b;
  }
  __syncthreads();
#pragma unroll
  for (int i = 0; i < 2; ++i) {
    int c = tid + i * 256;
    int n = c >> 3, koff = (c & 7) * 8;
    bf16x8 tv;
#pragma unroll
    for (int j = 0; j < 8; ++j) tv[j] = lds[(koff + j) * 72 + n];
    *(bf16x8*)(wT + (size_t)(nbase + tn * 64 + n) * 1024 + tk * 64 + koff) = tv;
  }
}

// Single-matrix variant for wo (1024x1024), launched after attn (aliases vt).
__global__ __launch_bounds__(256) void prep_wo(const float* __restrict__ w,
                                               bf16* __restrict__ wT) {
  __shared__ __align__(16) bf16 lds[64 * 72];
  int tk = blockIdx.x >> 4, tn = blockIdx.x & 15;
  int tid = threadIdx.x;
#pragma unroll
  for (int i = 0; i < 4; ++i) {
    int c = tid + i * 256;
    int kr = c >> 4, n4 = (c & 15) * 4;
    f32x4 v = *(const f32x4*)(w + (size_t)(tk * 64 + kr) * 1024 + tn * 64 + n4);
    bf16x4 b;
#pragma unroll
    for (int j = 0; j < 4; ++j) b[j] = (bf16)v[j];
    *(bf16x4*)(lds + kr * 72 + n4) = b;
  }
  __syncthreads();
#pragma unroll
  for (int i = 0; i < 2; ++i) {
    int c = tid + i * 256;
    int n = c >> 3, koff = (c & 7) * 8;
    bf16x8 tv;
#pragma unroll
    for (int j = 0; j < 8; ++j) tv[j] = lds[(koff + j) * 72 + n];
    *(bf16x8*)(wT + (size_t)(tn * 64 + n) * 1024 + tk * 64 + koff) = tv;
  }
}

// ---------------------------------------------------------------------------
// Fused QKV projection, bf16 pre-transposed weights. Grid (64, 12).
// Round-6: attn-style async staging — next k-tile's global loads are issued
// into registers BEFORE the MFMA section; LDS writes happen after a raw
// s_barrier (no vmcnt drain), so HBM latency hides under the MFMAs.
__global__ __launch_bounds__(256) void gemm_qkv(const float* __restrict__ x,
                                                const bf16* __restrict__ wT,
                                                bf16* __restrict__ qb,
                                                bf16* __restrict__ kvb) {
  __shared__ __align__(16) bf16 As[128 * 72];
  __shared__ __align__(16) bf16 Bs[128 * 72];
  int by = blockIdx.y;
  int n0 = by * 128;  // row into wT[1536][1024]
  bf16* Out;
  int ostride, ocol0;
  if (by < 8) {
    Out = qb; ostride = 1024; ocol0 = by * 128;
  } else if (by < 10) {
    Out = kvb; ostride = 512; ocol0 = (by - 8) * 128;
  } else {
    Out = kvb; ostride = 512; ocol0 = 256 + (by - 10) * 128;
  }
  int m0 = blockIdx.x * 128;
  int tid = threadIdx.x;
  int wave = tid >> 6, lane = tid & 63;
  int quad = lane >> 4, lr = lane & 15;
  int wr = (wave >> 1) * 64, wc = (wave & 1) * 64;
  int arow = tid >> 4, aoff = (tid & 15) * 4;  // A staging coords (+32 rows x8)
  int brow = tid >> 3, boff = (tid & 7) * 8;   // B staging coords (+32 rows x4)

  f32x4 acc[4][4];
  const f32x4 z = {0.f, 0.f, 0.f, 0.f};
#pragma unroll
  for (int i = 0; i < 4; ++i)
#pragma unroll
    for (int j = 0; j < 4; ++j) acc[i][j] = z;

  f32x4 sa[8];
  bf16x8 sb[4];
  // ---- prologue: stage k0 = 0
#pragma unroll
  for (int i = 0; i < 8; ++i)
    sa[i] = *(const f32x4*)(x + (size_t)(m0 + arow + i * 16) * 1024 + aoff);
#pragma unroll
  for (int i = 0; i < 4; ++i)
    sb[i] = *(const bf16x8*)(wT + (size_t)(n0 + brow + i * 32) * 1024 + boff);
#pragma unroll
  for (int i = 0; i < 8; ++i) {
    bf16x4 a16;
#pragma unroll
    for (int j = 0; j < 4; ++j) a16[j] = (bf16)sa[i][j];
    *(bf16x4*)(As + (arow + i * 16) * 72 + aoff) = a16;
  }
#pragma unroll
  for (int i = 0; i < 4; ++i) *(bf16x8*)(Bs + (brow + i * 32) * 72 + boff) = sb[i];
  asm volatile("s_waitcnt lgkmcnt(0)" ::: "memory");
  __builtin_amdgcn_s_barrier();
  __builtin_amdgcn_sched_barrier(0);

  for (int k0 = 0; k0 < 1024; k0 += 64) {
    bool pf = (k0 + 64 < 1024);
    if (pf) {
#pragma unroll
      for (int i = 0; i < 8; ++i)
        sa[i] = *(const f32x4*)(x + (size_t)(m0 + arow + i * 16) * 1024 + k0 + 64 + aoff);
#pragma unroll
      for (int i = 0; i < 4; ++i)
        sb[i] = *(const bf16x8*)(wT + (size_t)(n0 + brow + i * 32) * 1024 + k0 + 64 + boff);
    }
#pragma unroll
    for (int kx = 0; kx < 2; ++kx) {
      bf16x8 af[4], bfr[4];
#pragma unroll
      for (int t = 0; t < 4; ++t) {
        af[t] = *(const bf16x8*)(As + (wr + t * 16 + lr) * 72 + kx * 32 + quad * 8);
        bfr[t] = *(const bf16x8*)(Bs + (wc + t * 16 + lr) * 72 + kx * 32 + quad * 8);
      }
      __builtin_amdgcn_s_setprio(1);
#pragma unroll
      for (int rt = 0; rt < 4; ++rt)
#pragma unroll
        for (int ct = 0; ct < 4; ++ct)
          acc[rt][ct] = __builtin_amdgcn_mfma_f32_16x16x32_bf16(af[rt], bfr[ct],
                                                                acc[rt][ct], 0, 0, 0);
      __builtin_amdgcn_s_setprio(0);
    }
    // all waves consumed As/Bs for tile k0 (ds_reads drained before MFMAs)
    __builtin_amdgcn_s_barrier();
    __builtin_amdgcn_sched_barrier(0);
    if (pf) {
      // compiler inserts s_waitcnt vmcnt as sa/sb are first used here
#pragma unroll
      for (int i = 0; i < 8; ++i) {
        bf16x4 a16;
#pragma unroll
        for (int j = 0; j < 4; ++j) a16[j] = (bf16)sa[i][j];
        *(bf16x4*)(As + (arow + i * 16) * 72 + aoff) = a16;
      }
#pragma unroll
      for (int i = 0; i < 4; ++i) *(bf16x8*)(Bs + (brow + i * 32) * 72 + boff) = sb[i];
      asm volatile("s_waitcnt lgkmcnt(0)" ::: "memory");
    }
    __builtin_amdgcn_s_barrier();
    __builtin_amdgcn_sched_barrier(0);
  }
#pragma unroll
  for (int rt = 0; rt < 4; ++rt)
#pragma unroll
    for (int ct = 0; ct < 4; ++ct)
#pragma unroll
      for (int r = 0; r < 4; ++r) {
        int row = m0 + wr + rt * 16 + quad * 4 + r;
        int col = ocol0 + wc + ct * 16 + lr;
        Out[(size_t)row * ostride + col] = (bf16)acc[rt][ct][r];
      }
}

// ---------------------------------------------------------------------------
// Output projection: A = attn output (bf16), B^T = woT bf16, C = float out.
// Same async-staging structure (both operands bf16).
__global__ __launch_bounds__(256) void gemm_out(const bf16* __restrict__ A,
                                                const bf16* __restrict__ Bt,
                                                float* __restrict__ C) {
  __shared__ __align__(16) bf16 As[128 * 72];
  __shared__ __align__(16) bf16 Bs[128 * 72];
  int m0 = blockIdx.x * 128, n0 = blockIdx.y * 128;
  int tid = threadIdx.x;
  int wave = tid >> 6, lane = tid & 63;
  int quad = lane >> 4, lr = lane & 15;
  int wr = (wave >> 1) * 64, wc = (wave & 1) * 64;
  int brow = tid >> 3, boff = (tid & 7) * 8;

  f32x4 acc[4][4];
  const f32x4 z = {0.f, 0.f, 0.f, 0.f};
#pragma unroll
  for (int i = 0; i < 4; ++i)
#pragma unroll
    for (int j = 0; j < 4; ++j) acc[i][j] = z;

  bf16x8 sa[4], sb[4];
#pragma unroll
  for (int i = 0; i < 4; ++i) {
    sa[i] = *(const bf16x8*)(A + (size_t)(m0 + brow + i * 32) * 1024 + boff);
    sb[i] = *(const bf16x8*)(Bt + (size_t)(n0 + brow + i * 32) * 1024 + boff);
  }
#pragma unroll
  for (int i = 0; i < 4; ++i) {
    *(bf16x8*)(As + (brow + i * 32) * 72 + boff) = sa[i];
    *(bf16x8*)(Bs + (brow + i * 32) * 72 + boff) = sb[i];
  }
  asm volatile("s_waitcnt lgkmcnt(0)" ::: "memory");
  __builtin_amdgcn_s_barrier();
  __builtin_amdgcn_sched_barrier(0);

  for (int k0 = 0; k0 < 1024; k0 += 64) {
    bool pf = (k0 + 64 < 1024);
    if (pf) {
#pragma unroll
      for (int i = 0; i < 4; ++i) {
        sa[i] = *(const bf16x8*)(A + (size_t)(m0 + brow + i * 32) * 1024 + k0 + 64 + boff);
        sb[i] = *(const bf16x8*)(Bt + (size_t)(n0 + brow + i * 32) * 1024 + k0 + 64 + boff);
      }
    }
#pragma unroll
    for (int kx = 0; kx < 2; ++kx) {
      bf16x8 af[4], bfr[4];
#pragma unroll
      for (int t = 0; t < 4; ++t) {
        af[t] = *(const bf16x8*)(As + (wr + t * 16 + lr) * 72 + kx * 32 + quad * 8);
        bfr[t] = *(const bf16x8*)(Bs + (wc + t * 16 + lr) * 72 + kx * 32 + quad * 8);
      }
      __builtin_amdgcn_s_setprio(1);
#pragma unroll
      for (int rt = 0; rt < 4; ++rt)
#pragma unroll
        for (int ct = 0; ct < 4; ++ct)
          acc[rt][ct] = __builtin_amdgcn_mfma_f32_16x16x32_bf16(af[rt], bfr[ct],
                                                                acc[rt][ct], 0, 0, 0);
      __builtin_amdgcn_s_setprio(0);
    }
    __builtin_amdgcn_s_barrier();
    __builtin_amdgcn_sched_barrier(0);
    if (pf) {
#pragma unroll
      for (int i = 0; i < 4; ++i) {
        *(bf16x8*)(As + (brow + i * 32) * 72 + boff) = sa[i];
        *(bf16x8*)(Bs + (brow + i * 32) * 72 + boff) = sb[i];
      }
      asm volatile("s_waitcnt lgkmcnt(0)" ::: "memory");
    }
    __builtin_amdgcn_s_barrier();
    __builtin_amdgcn_sched_barrier(0);
  }
#pragma unroll
  for (int rt = 0; rt < 4; ++rt)
#pragma unroll
    for (int ct = 0; ct < 4; ++ct)
#pragma unroll
      for (int r = 0; r < 4; ++r) {
        int row = m0 + wr + rt * 16 + quad * 4 + r;
        int col = n0 + wc + ct * 16 + lr;
        C[(size_t)row * 1024 + col] = acc[rt][ct][r];
      }
}

// ---------------------------------------------------------------------------
// V transpose: kv [B*N][512] -> vt [B][HKV][D][N].  Also resets work queue.
__global__ __launch_bounds__(256) void transpose_v(const bf16* __restrict__ kv,
                                                   bf16* __restrict__ vt) {
  __shared__ __align__(16) bf16 lds[64 * 72];
  if (blockIdx.x == 0 && blockIdx.y == 0 && threadIdx.x == 0) g_ctr = 0;
  int nt = blockIdx.x;
  int bh = blockIdx.y;
  int b = bh >> 2, hkv = bh & 3;
  int tid = threadIdx.x;
#pragma unroll
  for (int i = 0; i < 2; ++i) {
    int c = tid + i * 256;
    int tok = c >> 3, off = (c & 7) * 8;
    *(bf16x8*)(lds + tok * 72 + off) =
        *(const bf16x8*)(kv + (size_t)(b * N_ + nt * 64 + tok) * 512 + 256 + hkv * 64 + off);
  }
  __syncthreads();
#pragma unroll
  for (int i = 0; i < 2; ++i) {
    int c = tid + i * 256;
    int d = c >> 3, toff = (c & 7) * 8;
    bf16x8 tv;
#pragma unroll
    for (int j = 0; j < 8; ++j) tv[j] = lds[(toff + j) * 72 + d];
    *(bf16x8*)(vt + ((size_t)bh * 64 + d) * N_ + nt * 64 + toff) = tv;
  }
}

// ---------------------------------------------------------------------------
// Per-head RMSNorm + RoPE, in place — VECTORIZED (G13): 8 lanes per head,
// bf16x8 per lane (16 B). RMS reduce = 3 shfls in the octet; RoPE partner
// d+-32 = shfl_xor(xn, 4); sign = -(e<4). Grid 5120 x 256 (32 heads/block).
__global__ __launch_bounds__(256) void norm_rope(bf16* __restrict__ q,
                                                 bf16* __restrict__ kv) {
  int tid = threadIdx.x;
  int g = (blockIdx.x << 5) + (tid >> 3);  // global head id, 163840 total
  int e = tid & 7;                          // octet index within head
  int t = g / 20;
  int sub = g - t * 20;
  int n = t & (N_ - 1);
  bf16* ptr;
  float oscale;
  if (sub < 16) {
    ptr = q + (size_t)t * 1024 + sub * 64;
    oscale = QSCALE;
  } else {
    ptr = kv + (size_t)t * 512 + (sub - 16) * 64;
    oscale = 1.0f;
  }
  bf16x8 v = *(const bf16x8*)(ptr + e * 8);
  float xv[8];
  float ss = 0.f;
#pragma unroll
  for (int i = 0; i < 8; ++i) {
    xv[i] = (float)v[i];
    ss += xv[i] * xv[i];
  }
  ss += __shfl_xor(ss, 1);
  ss += __shfl_xor(ss, 2);
  ss += __shfl_xor(ss, 4);
  float rn = rsqrtf(ss * (1.0f / 64.0f) + 1.1920929e-07f);
  float base = (float)((e & 3) * 8);  // d mod 32 base for this octet
  bf16x8 o;
#pragma unroll
  for (int i = 0; i < 8; ++i) {
    float xn = xv[i] * rn;
    float pr = __shfl_xor(xn, 4);  // partner element d +- 32 (rn is head-uniform)
    float rot = (e < 4) ? -pr : pr;
    float ang = (float)n * exp2f(-0.41524101186092029f * (base + (float)i));
    float sv, cv;
    __sincosf(ang, &sv, &cv);
    o[i] = (bf16)((xn * cv + rot * sv) * oscale);
  }
  *(bf16x8*)(ptr + e * 8) = o;
}

// ---------------------------------------------------------------------------
// Causal flash attention with GQA — TRANSPOSED dataflow (S^T / O^T),
// persistent work-queue + XOR-swizzled LDS + defer-max. UNCHANGED from the
// verified round-6 kernel (VALU-bound at 54%; next lever is structural).
__global__ __launch_bounds__(256) void attn(bf16* __restrict__ q,
                                            const bf16* __restrict__ kv,
                                            const bf16* __restrict__ vt) {
  __shared__ __align__(16) bf16 Ks[64 * 64];  // [key][d], swizzled
  __shared__ __align__(16) bf16 Vs[64 * 64];  // [d][key], swizzled
  __shared__ __align__(16) bf16 Ps[64 * 64];  // [q-row][key], swizzled
  __shared__ int s_item;
  int tid = threadIdx.x;
  int wave = tid >> 6, lane = tid & 63;
  int quad = lane >> 4, lr = lane & 15;
  int srow = tid >> 3, soff = (tid & 7) * 8;
  int su = ((tid & 7) ^ (srow & 7)) * 8;  // swizzled LDS unit (same for srow+32)
  int e7 = lr & 7;                        // read-side row XOR key
  const f32x4 z = {0.f, 0.f, 0.f, 0.f};

  while (true) {
    if (tid == 0) s_item = atomicAdd(&g_ctr, 1);
    __syncthreads();  // publish s_item; also: all waves done with prev item's LDS
    int item = s_item;
    if (item >= 2048) break;
    int j = 31 - (item >> 6);  // 64-row q-tile index, longest first
    int rr = item & 63;
    int b = rr & 3, h = rr >> 2, hkv = h >> 2;
    int qrow0 = j * 64 + wave * 16;  // this wave's first q-row
    int nkt = j + 1;

    // Q fragments (B-operand = Q^T): lane holds Q[qrow0+lr][kx*32+quad*8..]
    bf16x8 qf[2];
#pragma unroll
    for (int kx = 0; kx < 2; ++kx)
      qf[kx] = *(const bf16x8*)(
          q + ((size_t)(b * N_ + qrow0 + lr) * H_ + h) * D_ + kx * 32 + quad * 8);

    f32x4 acc[4];  // acc[dt] = O^T tile: row d=dt*16+quad*4+r, col qrow=lr
    float m_i = NEGINF, l_i = 0.f;
#pragma unroll
    for (int dt = 0; dt < 4; ++dt) acc[dt] = z;

    // staging pointers (strength-reduced; advance per tile)
    const bf16* kp = kv + (size_t)(b * N_ + srow) * 512 + hkv * 64 + soff;
    const bf16* vp = vt + ((size_t)(b * HKV_ + hkv) * 64 + srow) * N_ + soff;

    // ---- prologue: stage tile 0 synchronously
    bf16x8 sk0, sk1, sv0, sv1;
    sk0 = *(const bf16x8*)(kp);
    sk1 = *(const bf16x8*)(kp + 32 * 512);
    sv0 = *(const bf16x8*)(vp);
    sv1 = *(const bf16x8*)(vp + 32 * N_);
    *(bf16x8*)(Ks + srow * 64 + su) = sk0;
    *(bf16x8*)(Ks + (srow + 32) * 64 + su) = sk1;
    *(bf16x8*)(Vs + srow * 64 + su) = sv0;
    *(bf16x8*)(Vs + (srow + 32) * 64 + su) = sv1;
    asm volatile("s_waitcnt lgkmcnt(0)" ::: "memory");
    __builtin_amdgcn_s_barrier();
    __builtin_amdgcn_sched_barrier(0);

    for (int kt = 0; kt < nkt; ++kt) {
      // ---- issue NEXT tile's global loads early (in flight across compute)
      bool pf = (kt + 1 < nkt);
      if (pf) {
        kp += 64 * 512;
        vp += 64;
        sk0 = *(const bf16x8*)(kp);
        sk1 = *(const bf16x8*)(kp + 32 * 512);
        sv0 = *(const bf16x8*)(vp);
        sv1 = *(const bf16x8*)(vp + 32 * N_);
      }

      // S^T = K·Q^T: st[ct] — key = kt*64 + ct*16 + quad*4 + r, qrow col = lr
      f32x4 st[4];
#pragma unroll
      for (int ct = 0; ct < 4; ++ct) st[ct] = z;
#pragma unroll
      for (int kx = 0; kx < 2; ++kx) {
        bf16x8 kf[4];
#pragma unroll
        for (int ct = 0; ct < 4; ++ct)
          kf[ct] = *(const bf16x8*)(Ks + (ct * 16 + lr) * 64 + (((kx * 4 + quad) ^ e7) * 8));
        __builtin_amdgcn_s_setprio(1);
#pragma unroll
        for (int ct = 0; ct < 4; ++ct)
          st[ct] = __builtin_amdgcn_mfma_f32_16x16x32_bf16(kf[ct], qf[kx], st[ct], 0, 0, 0);
        __builtin_amdgcn_s_setprio(0);
      }
      // Causal mask — only the diagonal tile kt == j crosses the diagonal
      if (kt == j) {
        int qrow = qrow0 + lr;
#pragma unroll
        for (int ct = 0; ct < 4; ++ct)
#pragma unroll
          for (int r = 0; r < 4; ++r) {
            int key = kt * 64 + ct * 16 + quad * 4 + r;
            if (key > qrow) st[ct][r] = NEGINF;
          }
      }
      // Online softmax with defer-max (T13): rescale only on >8 max growth.
      float mx = NEGINF;
#pragma unroll
      for (int ct = 0; ct < 4; ++ct)
#pragma unroll
        for (int r = 0; r < 4; ++r) mx = fmaxf(mx, st[ct][r]);
      mx = fmaxf(mx, __shfl_xor(mx, 16));
      mx = fmaxf(mx, __shfl_xor(mx, 32));
      if (__any(mx > m_i + 8.0f)) {
        float mnew = fmaxf(m_i, mx);
        float alpha = exp2f(m_i - mnew);
        m_i = mnew;
        l_i *= alpha;
#pragma unroll
        for (int dt = 0; dt < 4; ++dt)
#pragma unroll
          for (int r = 0; r < 4; ++r) acc[dt][r] *= alpha;
      }
      float rs = 0.f;
#pragma unroll
      for (int ct = 0; ct < 4; ++ct)
#pragma unroll
        for (int r = 0; r < 4; ++r) {
          float p = exp2f(st[ct][r] - m_i);
          st[ct][r] = p;
          rs += p;
        }
      rs += __shfl_xor(rs, 16);
      rs += __shfl_xor(rs, 32);
      l_i += rs;
      // P^T -> Ps[qrow][key] (swizzled): b64 writes, keys quad*4+r contiguous
#pragma unroll
      for (int ct = 0; ct < 4; ++ct) {
        bf16x4 pk;
#pragma unroll
        for (int r = 0; r < 4; ++r) pk[r] = (bf16)st[ct][r];
        int pu = (((ct * 2) + (quad >> 1)) ^ e7) * 8 + (quad & 1) * 4;
        *(bf16x4*)(Ps + (wave * 16 + lr) * 64 + pu) = pk;
      }
      // Wave-local LDS ordering (rows wave-private, guard wave-uniform)
      asm volatile("s_waitcnt lgkmcnt(0)" ::: "memory");
      // O^T += V^T·P^T
#pragma unroll
      for (int kx = 0; kx < 2; ++kx) {
        bf16x8 vf[4], pfr;
#pragma unroll
        for (int dt = 0; dt < 4; ++dt)
          vf[dt] = *(const bf16x8*)(Vs + (dt * 16 + lr) * 64 + (((kx * 4 + quad) ^ e7) * 8));
        pfr = *(const bf16x8*)(Ps + (wave * 16 + lr) * 64 + (((kx * 4 + quad) ^ e7) * 8));
        __builtin_amdgcn_s_setprio(1);
#pragma unroll
        for (int dt = 0; dt < 4; ++dt)
          acc[dt] = __builtin_amdgcn_mfma_f32_16x16x32_bf16(vf[dt], pfr, acc[dt], 0, 0, 0);
        __builtin_amdgcn_s_setprio(0);
      }

      // ---- all waves done READING tile kt; prefetch loads stay in flight
      __builtin_amdgcn_s_barrier();
      __builtin_amdgcn_sched_barrier(0);
      if (pf) {
        // compiler inserts s_waitcnt vmcnt(0) before first use of sk*/sv*
        *(bf16x8*)(Ks + srow * 64 + su) = sk0;
        *(bf16x8*)(Ks + (srow + 32) * 64 + su) = sk1;
        *(bf16x8*)(Vs + srow * 64 + su) = sv0;
        *(bf16x8*)(Vs + (srow + 32) * 64 + su) = sv1;
        asm volatile("s_waitcnt lgkmcnt(0)" ::: "memory");
      }
      __builtin_amdgcn_s_barrier();  // tile kt+1 visible to all waves
      __builtin_amdgcn_sched_barrier(0);
    }

    // Epilogue: y = O / l — lane owns q-row lr, d = dt*16+quad*4+r
    float inv = 1.0f / l_i;
    int qrow = qrow0 + lr;
#pragma unroll
    for (int dt = 0; dt < 4; ++dt) {
      bf16x4 ov;
#pragma unroll
      for (int r = 0; r < 4; ++r) ov[r] = (bf16)(acc[dt][r] * inv);
      *(bf16x4*)(q + ((size_t)(b * N_ + qrow) * H_ + h) * D_ + dt * 16 + quad * 4) = ov;
    }
  }
}

// ---------------------------------------------------------------------------
extern "C" void kernel_launch(void* const* d_in, const int* in_sizes, int n_in,
                              void* d_out, int out_size, void* d_ws, size_t ws_size,
                              hipStream_t stream) {
  // Inputs FP32; output FP32. Intermediates bf16.
  const float* x = (const float*)d_in[0];
  const float* wq = (const float*)d_in[1];
  const float* wk = (const float*)d_in[2];
  const float* wv = (const float*)d_in[3];
  const float* wo = (const float*)d_in[4];
  float* out = (float*)d_out;
  char* ws = (char*)d_ws;
  // ws (28 MB): q/y 16 MB [0,16M) | kv 8 MB [16M,24M) | region [24M,28M) is
  // time-shared: wqkvT (3 MB) -> vt (4 MB) -> woT (2 MB).
  bf16* q = (bf16*)(ws);
  bf16* kv = (bf16*)(ws + 16777216);
  bf16* vt = (bf16*)(ws + 25165824);
  bf16* wqkvT = (bf16*)(ws + 25165824);
  bf16* woT = (bf16*)(ws + 25165824);

  prep_qkv<<<dim3(384), 256, 0, stream>>>(wq, wk, wv, wqkvT);
  gemm_qkv<<<dim3(64, 12), 256, 0, stream>>>(x, wqkvT, q, kv);
  norm_rope<<<dim3(5120), 256, 0, stream>>>(q, kv);
  transpose_v<<<dim3(32, 16), 256, 0, stream>>>(kv, vt);
  attn<<<dim3(1536), 256, 0, stream>>>(q, kv, vt);
  prep_wo<<<dim3(256), 256, 0, stream>>>(wo, woT);
  gemm_out<<<dim3(64, 8), 256, 0, stream>>>(q, woT, out);
}

// Round 8
// 257.746 us; speedup vs baseline: 2.2945x; 1.0296x over previous
//
#include <hip/hip_runtime.h>

typedef __bf16 bf16;
typedef __bf16 bf16x8 __attribute__((ext_vector_type(8)));
typedef __bf16 bf16x4 __attribute__((ext_vector_type(4)));
typedef float f32x4 __attribute__((ext_vector_type(4)));

#define B_ 4
#define N_ 2048
#define C_ 1024
#define H_ 16
#define HKV_ 4
#define D_ 64

// fold: 1.5 (qk_gain) * 0.125 (1/sqrt(64)) * log2(e)  -> use exp2f in softmax
#define QSCALE 0.2705053201666806f
#define NEGINF (-1.0e30f)

// work queue for persistent attn (reset by transpose_v each launch)
__device__ int g_ctr;

// ---------------------------------------------------------------------------
// Weight prep: w [1024 k][ncols n] f32 -> wT [n][1024 k] bf16 (+ convert).
__global__ __launch_bounds__(256) void prep_qkv(const float* __restrict__ wq,
                                                const float* __restrict__ wk,
                                                const float* __restrict__ wv,
                                                bf16* __restrict__ wT) {
  __shared__ __align__(16) bf16 lds[64 * 72];
  int bx = blockIdx.x;
  const float* w;
  int ncols, tk, tn, nbase;
  if (bx < 256) {
    w = wq; ncols = 1024; tk = bx >> 4; tn = bx & 15; nbase = 0;
  } else if (bx < 320) {
    int t = bx - 256;
    w = wk; ncols = 256; tk = t >> 2; tn = t & 3; nbase = 1024;
  } else {
    int t = bx - 320;
    w = wv; ncols = 256; tk = t >> 2; tn = t & 3; nbase = 1280;
  }
  int tid = threadIdx.x;
#pragma unroll
  for (int i = 0; i < 4; ++i) {
    int c = tid + i * 256;
    int kr = c >> 4, n4 = (c & 15) * 4;
    f32x4 v = *(const f32x4*)(w + (size_t)(tk * 64 + kr) * ncols + tn * 64 + n4);
    bf16x4 b;
#pragma unroll
    for (int j = 0; j < 4; ++j) b[j] = (bf16)v[j];
    *(bf16x4*)(lds + kr * 72 + n4) = b;
  }
  __syncthreads();
#pragma unroll
  for (int i = 0; i < 2; ++i) {
    int c = tid + i * 256;
    int n = c >> 3, koff = (c & 7) * 8;
    bf16x8 tv;
#pragma unroll
    for (int j = 0; j < 8; ++j) tv[j] = lds[(koff + j) * 72 + n];
    *(bf16x8*)(wT + (size_t)(nbase + tn * 64 + n) * 1024 + tk * 64 + koff) = tv;
  }
}

// Single-matrix variant for wo (1024x1024), launched after attn (aliases vt).
__global__ __launch_bounds__(256) void prep_wo(const float* __restrict__ w,
                                               bf16* __restrict__ wT) {
  __shared__ __align__(16) bf16 lds[64 * 72];
  int tk = blockIdx.x >> 4, tn = blockIdx.x & 15;
  int tid = threadIdx.x;
#pragma unroll
  for (int i = 0; i < 4; ++i) {
    int c = tid + i * 256;
    int kr = c >> 4, n4 = (c & 15) * 4;
    f32x4 v = *(const f32x4*)(w + (size_t)(tk * 64 + kr) * 1024 + tn * 64 + n4);
    bf16x4 b;
#pragma unroll
    for (int j = 0; j < 4; ++j) b[j] = (bf16)v[j];
    *(bf16x4*)(lds + kr * 72 + n4) = b;
  }
  __syncthreads();
#pragma unroll
  for (int i = 0; i < 2; ++i) {
    int c = tid + i * 256;
    int n = c >> 3, koff = (c & 7) * 8;
    bf16x8 tv;
#pragma unroll
    for (int j = 0; j < 8; ++j) tv[j] = lds[(koff + j) * 72 + n];
    *(bf16x8*)(wT + (size_t)(tn * 64 + n) * 1024 + tk * 64 + koff) = tv;
  }
}

// ---------------------------------------------------------------------------
// Fused QKV projection, bf16 pre-transposed weights. Grid (64, 12).
// Attn-style async staging: next k-tile's global loads are issued into
// registers BEFORE the MFMA section; LDS writes after a raw s_barrier.
__global__ __launch_bounds__(256) void gemm_qkv(const float* __restrict__ x,
                                                const bf16* __restrict__ wT,
                                                bf16* __restrict__ qb,
                                                bf16* __restrict__ kvb) {
  __shared__ __align__(16) bf16 As[128 * 72];
  __shared__ __align__(16) bf16 Bs[128 * 72];
  int by = blockIdx.y;
  int n0 = by * 128;  // row into wT[1536][1024]
  bf16* Out;
  int ostride, ocol0;
  if (by < 8) {
    Out = qb; ostride = 1024; ocol0 = by * 128;
  } else if (by < 10) {
    Out = kvb; ostride = 512; ocol0 = (by - 8) * 128;
  } else {
    Out = kvb; ostride = 512; ocol0 = 256 + (by - 10) * 128;
  }
  int m0 = blockIdx.x * 128;
  int tid = threadIdx.x;
  int wave = tid >> 6, lane = tid & 63;
  int quad = lane >> 4, lr = lane & 15;
  int wr = (wave >> 1) * 64, wc = (wave & 1) * 64;
  int arow = tid >> 4, aoff = (tid & 15) * 4;  // A staging coords (+16 rows x8)
  int brow = tid >> 3, boff = (tid & 7) * 8;   // B staging coords (+32 rows x4)

  f32x4 acc[4][4];
  const f32x4 z = {0.f, 0.f, 0.f, 0.f};
#pragma unroll
  for (int i = 0; i < 4; ++i)
#pragma unroll
    for (int j = 0; j < 4; ++j) acc[i][j] = z;

  f32x4 sa[8];
  bf16x8 sb[4];
  // ---- prologue: stage k0 = 0
#pragma unroll
  for (int i = 0; i < 8; ++i)
    sa[i] = *(const f32x4*)(x + (size_t)(m0 + arow + i * 16) * 1024 + aoff);
#pragma unroll
  for (int i = 0; i < 4; ++i)
    sb[i] = *(const bf16x8*)(wT + (size_t)(n0 + brow + i * 32) * 1024 + boff);
#pragma unroll
  for (int i = 0; i < 8; ++i) {
    bf16x4 a16;
#pragma unroll
    for (int j = 0; j < 4; ++j) a16[j] = (bf16)sa[i][j];
    *(bf16x4*)(As + (arow + i * 16) * 72 + aoff) = a16;
  }
#pragma unroll
  for (int i = 0; i < 4; ++i) *(bf16x8*)(Bs + (brow + i * 32) * 72 + boff) = sb[i];
  asm volatile("s_waitcnt lgkmcnt(0)" ::: "memory");
  __builtin_amdgcn_s_barrier();
  __builtin_amdgcn_sched_barrier(0);

  for (int k0 = 0; k0 < 1024; k0 += 64) {
    bool pf = (k0 + 64 < 1024);
    if (pf) {
#pragma unroll
      for (int i = 0; i < 8; ++i)
        sa[i] = *(const f32x4*)(x + (size_t)(m0 + arow + i * 16) * 1024 + k0 + 64 + aoff);
#pragma unroll
      for (int i = 0; i < 4; ++i)
        sb[i] = *(const bf16x8*)(wT + (size_t)(n0 + brow + i * 32) * 1024 + k0 + 64 + boff);
    }
#pragma unroll
    for (int kx = 0; kx < 2; ++kx) {
      bf16x8 af[4], bfr[4];
#pragma unroll
      for (int t = 0; t < 4; ++t) {
        af[t] = *(const bf16x8*)(As + (wr + t * 16 + lr) * 72 + kx * 32 + quad * 8);
        bfr[t] = *(const bf16x8*)(Bs + (wc + t * 16 + lr) * 72 + kx * 32 + quad * 8);
      }
      __builtin_amdgcn_s_setprio(1);
#pragma unroll
      for (int rt = 0; rt < 4; ++rt)
#pragma unroll
        for (int ct = 0; ct < 4; ++ct)
          acc[rt][ct] = __builtin_amdgcn_mfma_f32_16x16x32_bf16(af[rt], bfr[ct],
                                                                acc[rt][ct], 0, 0, 0);
      __builtin_amdgcn_s_setprio(0);
    }
    // all waves consumed As/Bs for tile k0 (ds_reads drained before MFMAs)
    __builtin_amdgcn_s_barrier();
    __builtin_amdgcn_sched_barrier(0);
    if (pf) {
      // compiler inserts s_waitcnt vmcnt as sa/sb are first used here
#pragma unroll
      for (int i = 0; i < 8; ++i) {
        bf16x4 a16;
#pragma unroll
        for (int j = 0; j < 4; ++j) a16[j] = (bf16)sa[i][j];
        *(bf16x4*)(As + (arow + i * 16) * 72 + aoff) = a16;
      }
#pragma unroll
      for (int i = 0; i < 4; ++i) *(bf16x8*)(Bs + (brow + i * 32) * 72 + boff) = sb[i];
      asm volatile("s_waitcnt lgkmcnt(0)" ::: "memory");
    }
    __builtin_amdgcn_s_barrier();
    __builtin_amdgcn_sched_barrier(0);
  }
#pragma unroll
  for (int rt = 0; rt < 4; ++rt)
#pragma unroll
    for (int ct = 0; ct < 4; ++ct)
#pragma unroll
      for (int r = 0; r < 4; ++r) {
        int row = m0 + wr + rt * 16 + quad * 4 + r;
        int col = ocol0 + wc + ct * 16 + lr;
        Out[(size_t)row * ostride + col] = (bf16)acc[rt][ct][r];
      }
}

// ---------------------------------------------------------------------------
// Output projection: A = attn output (bf16), B^T = woT bf16, C = float out.
// Same async-staging structure (both operands bf16).
__global__ __launch_bounds__(256) void gemm_out(const bf16* __restrict__ A,
                                                const bf16* __restrict__ Bt,
                                                float* __restrict__ C) {
  __shared__ __align__(16) bf16 As[128 * 72];
  __shared__ __align__(16) bf16 Bs[128 * 72];
  int m0 = blockIdx.x * 128, n0 = blockIdx.y * 128;
  int tid = threadIdx.x;
  int wave = tid >> 6, lane = tid & 63;
  int quad = lane >> 4, lr = lane & 15;
  int wr = (wave >> 1) * 64, wc = (wave & 1) * 64;
  int brow = tid >> 3, boff = (tid & 7) * 8;

  f32x4 acc[4][4];
  const f32x4 z = {0.f, 0.f, 0.f, 0.f};
#pragma unroll
  for (int i = 0; i < 4; ++i)
#pragma unroll
    for (int j = 0; j < 4; ++j) acc[i][j] = z;

  bf16x8 sa[4], sb[4];
#pragma unroll
  for (int i = 0; i < 4; ++i) {
    sa[i] = *(const bf16x8*)(A + (size_t)(m0 + brow + i * 32) * 1024 + boff);
    sb[i] = *(const bf16x8*)(Bt + (size_t)(n0 + brow + i * 32) * 1024 + boff);
  }
#pragma unroll
  for (int i = 0; i < 4; ++i) {
    *(bf16x8*)(As + (brow + i * 32) * 72 + boff) = sa[i];
    *(bf16x8*)(Bs + (brow + i * 32) * 72 + boff) = sb[i];
  }
  asm volatile("s_waitcnt lgkmcnt(0)" ::: "memory");
  __builtin_amdgcn_s_barrier();
  __builtin_amdgcn_sched_barrier(0);

  for (int k0 = 0; k0 < 1024; k0 += 64) {
    bool pf = (k0 + 64 < 1024);
    if (pf) {
#pragma unroll
      for (int i = 0; i < 4; ++i) {
        sa[i] = *(const bf16x8*)(A + (size_t)(m0 + brow + i * 32) * 1024 + k0 + 64 + boff);
        sb[i] = *(const bf16x8*)(Bt + (size_t)(n0 + brow + i * 32) * 1024 + k0 + 64 + boff);
      }
    }
#pragma unroll
    for (int kx = 0; kx < 2; ++kx) {
      bf16x8 af[4], bfr[4];
#pragma unroll
      for (int t = 0; t < 4; ++t) {
        af[t] = *(const bf16x8*)(As + (wr + t * 16 + lr) * 72 + kx * 32 + quad * 8);
        bfr[t] = *(const bf16x8*)(Bs + (wc + t * 16 + lr) * 72 + kx * 32 + quad * 8);
      }
      __builtin_amdgcn_s_setprio(1);
#pragma unroll
      for (int rt = 0; rt < 4; ++rt)
#pragma unroll
        for (int ct = 0; ct < 4; ++ct)
          acc[rt][ct] = __builtin_amdgcn_mfma_f32_16x16x32_bf16(af[rt], bfr[ct],
                                                                acc[rt][ct], 0, 0, 0);
      __builtin_amdgcn_s_setprio(0);
    }
    __builtin_amdgcn_s_barrier();
    __builtin_amdgcn_sched_barrier(0);
    if (pf) {
#pragma unroll
      for (int i = 0; i < 4; ++i) {
        *(bf16x8*)(As + (brow + i * 32) * 72 + boff) = sa[i];
        *(bf16x8*)(Bs + (brow + i * 32) * 72 + boff) = sb[i];
      }
      asm volatile("s_waitcnt lgkmcnt(0)" ::: "memory");
    }
    __builtin_amdgcn_s_barrier();
    __builtin_amdgcn_sched_barrier(0);
  }
#pragma unroll
  for (int rt = 0; rt < 4; ++rt)
#pragma unroll
    for (int ct = 0; ct < 4; ++ct)
#pragma unroll
      for (int r = 0; r < 4; ++r) {
        int row = m0 + wr + rt * 16 + quad * 4 + r;
        int col = n0 + wc + ct * 16 + lr;
        C[(size_t)row * 1024 + col] = acc[rt][ct][r];
      }
}

// ---------------------------------------------------------------------------
// V transpose: kv [B*N][512] -> vt [B][HKV][D][N].  Also resets work queue.
__global__ __launch_bounds__(256) void transpose_v(const bf16* __restrict__ kv,
                                                   bf16* __restrict__ vt) {
  __shared__ __align__(16) bf16 lds[64 * 72];
  if (blockIdx.x == 0 && blockIdx.y == 0 && threadIdx.x == 0) g_ctr = 0;
  int nt = blockIdx.x;
  int bh = blockIdx.y;
  int b = bh >> 2, hkv = bh & 3;
  int tid = threadIdx.x;
#pragma unroll
  for (int i = 0; i < 2; ++i) {
    int c = tid + i * 256;
    int tok = c >> 3, off = (c & 7) * 8;
    *(bf16x8*)(lds + tok * 72 + off) =
        *(const bf16x8*)(kv + (size_t)(b * N_ + nt * 64 + tok) * 512 + 256 + hkv * 64 + off);
  }
  __syncthreads();
#pragma unroll
  for (int i = 0; i < 2; ++i) {
    int c = tid + i * 256;
    int d = c >> 3, toff = (c & 7) * 8;
    bf16x8 tv;
#pragma unroll
    for (int j = 0; j < 8; ++j) tv[j] = lds[(toff + j) * 72 + d];
    *(bf16x8*)(vt + ((size_t)bh * 64 + d) * N_ + nt * 64 + toff) = tv;
  }
}

// ---------------------------------------------------------------------------
// Per-head RMSNorm + RoPE, in place — VECTORIZED (G13): 8 lanes per head,
// bf16x8 per lane (16 B). RMS reduce = 3 shfls in the octet; RoPE partner
// d+-32 = shfl_xor(xn, 4); sign = -(e<4). Grid 5120 x 256 (32 heads/block).
__global__ __launch_bounds__(256) void norm_rope(bf16* __restrict__ q,
                                                 bf16* __restrict__ kv) {
  int tid = threadIdx.x;
  int g = (blockIdx.x << 5) + (tid >> 3);  // global head id, 163840 total
  int e = tid & 7;                          // octet index within head
  int t = g / 20;
  int sub = g - t * 20;
  int n = t & (N_ - 1);
  bf16* ptr;
  float oscale;
  if (sub < 16) {
    ptr = q + (size_t)t * 1024 + sub * 64;
    oscale = QSCALE;
  } else {
    ptr = kv + (size_t)t * 512 + (sub - 16) * 64;
    oscale = 1.0f;
  }
  bf16x8 v = *(const bf16x8*)(ptr + e * 8);
  float xv[8];
  float ss = 0.f;
#pragma unroll
  for (int i = 0; i < 8; ++i) {
    xv[i] = (float)v[i];
    ss += xv[i] * xv[i];
  }
  ss += __shfl_xor(ss, 1);
  ss += __shfl_xor(ss, 2);
  ss += __shfl_xor(ss, 4);
  float rn = rsqrtf(ss * (1.0f / 64.0f) + 1.1920929e-07f);
  float base = (float)((e & 3) * 8);  // d mod 32 base for this octet
  bf16x8 o;
#pragma unroll
  for (int i = 0; i < 8; ++i) {
    float xn = xv[i] * rn;
    float pr = __shfl_xor(xn, 4);  // partner element d +- 32 (rn is head-uniform)
    float rot = (e < 4) ? -pr : pr;
    float ang = (float)n * exp2f(-0.41524101186092029f * (base + (float)i));
    float sv, cv;
    __sincosf(ang, &sv, &cv);
    o[i] = (bf16)((xn * cv + rot * sv) * oscale);
  }
  *(bf16x8*)(ptr + e * 8) = o;
}

// ---------------------------------------------------------------------------
// Causal flash attention with GQA — TRANSPOSED dataflow (S^T / O^T),
// persistent work-queue + XOR-swizzled LDS.
// Round-7: NO-SHIFT softmax. RMS-norm bounds ||q||=||k||=8 exactly, so the
// exp2-domain score |s| <= 64*QSCALE = 17.32 and p = exp2(s) <= 1.6e5 —
// no overflow anywhere (f32 acc, bf16 P are floating; softmax is
// shift-invariant so the 2^max factor cancels in O = sum(p*v)/sum(p)).
// Removes the entire max-reduce + rescale + m_i machinery: per 16-score
// tile-lane this deletes 16 fmax + 2 cross-lane shfls + ballot + 16 subs
// and breaks the serial max->exp dependency.
__global__ __launch_bounds__(256) void attn(bf16* __restrict__ q,
                                            const bf16* __restrict__ kv,
                                            const bf16* __restrict__ vt) {
  __shared__ __align__(16) bf16 Ks[64 * 64];  // [key][d], swizzled
  __shared__ __align__(16) bf16 Vs[64 * 64];  // [d][key], swizzled
  __shared__ __align__(16) bf16 Ps[64 * 64];  // [q-row][key], swizzled
  __shared__ int s_item;
  int tid = threadIdx.x;
  int wave = tid >> 6, lane = tid & 63;
  int quad = lane >> 4, lr = lane & 15;
  int srow = tid >> 3, soff = (tid & 7) * 8;
  int su = ((tid & 7) ^ (srow & 7)) * 8;  // swizzled LDS unit (same for srow+32)
  int e7 = lr & 7;                        // read-side row XOR key
  const f32x4 z = {0.f, 0.f, 0.f, 0.f};

  while (true) {
    if (tid == 0) s_item = atomicAdd(&g_ctr, 1);
    __syncthreads();  // publish s_item; also: all waves done with prev item's LDS
    int item = s_item;
    if (item >= 2048) break;
    int j = 31 - (item >> 6);  // 64-row q-tile index, longest first
    int rr = item & 63;
    int b = rr & 3, h = rr >> 2, hkv = h >> 2;
    int qrow0 = j * 64 + wave * 16;  // this wave's first q-row
    int nkt = j + 1;

    // Q fragments (B-operand = Q^T): lane holds Q[qrow0+lr][kx*32+quad*8..]
    bf16x8 qf[2];
#pragma unroll
    for (int kx = 0; kx < 2; ++kx)
      qf[kx] = *(const bf16x8*)(
          q + ((size_t)(b * N_ + qrow0 + lr) * H_ + h) * D_ + kx * 32 + quad * 8);

    f32x4 acc[4];  // acc[dt] = O^T tile: row d=dt*16+quad*4+r, col qrow=lr
    float l_i = 0.f;
#pragma unroll
    for (int dt = 0; dt < 4; ++dt) acc[dt] = z;

    // staging pointers (strength-reduced; advance per tile)
    const bf16* kp = kv + (size_t)(b * N_ + srow) * 512 + hkv * 64 + soff;
    const bf16* vp = vt + ((size_t)(b * HKV_ + hkv) * 64 + srow) * N_ + soff;

    // ---- prologue: stage tile 0 synchronously
    bf16x8 sk0, sk1, sv0, sv1;
    sk0 = *(const bf16x8*)(kp);
    sk1 = *(const bf16x8*)(kp + 32 * 512);
    sv0 = *(const bf16x8*)(vp);
    sv1 = *(const bf16x8*)(vp + 32 * N_);
    *(bf16x8*)(Ks + srow * 64 + su) = sk0;
    *(bf16x8*)(Ks + (srow + 32) * 64 + su) = sk1;
    *(bf16x8*)(Vs + srow * 64 + su) = sv0;
    *(bf16x8*)(Vs + (srow + 32) * 64 + su) = sv1;
    asm volatile("s_waitcnt lgkmcnt(0)" ::: "memory");
    __builtin_amdgcn_s_barrier();
    __builtin_amdgcn_sched_barrier(0);

    for (int kt = 0; kt < nkt; ++kt) {
      // ---- issue NEXT tile's global loads early (in flight across compute)
      bool pf = (kt + 1 < nkt);
      if (pf) {
        kp += 64 * 512;
        vp += 64;
        sk0 = *(const bf16x8*)(kp);
        sk1 = *(const bf16x8*)(kp + 32 * 512);
        sv0 = *(const bf16x8*)(vp);
        sv1 = *(const bf16x8*)(vp + 32 * N_);
      }

      // S^T = K·Q^T: st[ct] — key = kt*64 + ct*16 + quad*4 + r, qrow col = lr
      f32x4 st[4];
#pragma unroll
      for (int ct = 0; ct < 4; ++ct) st[ct] = z;
#pragma unroll
      for (int kx = 0; kx < 2; ++kx) {
        bf16x8 kf[4];
#pragma unroll
        for (int ct = 0; ct < 4; ++ct)
          kf[ct] = *(const bf16x8*)(Ks + (ct * 16 + lr) * 64 + (((kx * 4 + quad) ^ e7) * 8));
        __builtin_amdgcn_s_setprio(1);
#pragma unroll
        for (int ct = 0; ct < 4; ++ct)
          st[ct] = __builtin_amdgcn_mfma_f32_16x16x32_bf16(kf[ct], qf[kx], st[ct], 0, 0, 0);
        __builtin_amdgcn_s_setprio(0);
      }
      // Causal mask — only the diagonal tile kt == j crosses the diagonal
      if (kt == j) {
        int qrow = qrow0 + lr;
#pragma unroll
        for (int ct = 0; ct < 4; ++ct)
#pragma unroll
          for (int r = 0; r < 4; ++r) {
            int key = kt * 64 + ct * 16 + quad * 4 + r;
            if (key > qrow) st[ct][r] = NEGINF;
          }
      }
      // No-shift softmax: p = exp2(s) directly (|s| <= 17.32 by RMS bound);
      // masked entries exp2(-1e30) = 0. l accumulates unnormalized.
      float rs = 0.f;
#pragma unroll
      for (int ct = 0; ct < 4; ++ct)
#pragma unroll
        for (int r = 0; r < 4; ++r) {
          float p = exp2f(st[ct][r]);
          st[ct][r] = p;
          rs += p;
        }
      rs += __shfl_xor(rs, 16);
      rs += __shfl_xor(rs, 32);
      l_i += rs;
      // P^T -> Ps[qrow][key] (swizzled): b64 writes, keys quad*4+r contiguous
#pragma unroll
      for (int ct = 0; ct < 4; ++ct) {
        bf16x4 pk;
#pragma unroll
        for (int r = 0; r < 4; ++r) pk[r] = (bf16)st[ct][r];
        int pu = (((ct * 2) + (quad >> 1)) ^ e7) * 8 + (quad & 1) * 4;
        *(bf16x4*)(Ps + (wave * 16 + lr) * 64 + pu) = pk;
      }
      // Wave-local LDS ordering (rows wave-private, guard wave-uniform)
      asm volatile("s_waitcnt lgkmcnt(0)" ::: "memory");
      // O^T += V^T·P^T
#pragma unroll
      for (int kx = 0; kx < 2; ++kx) {
        bf16x8 vf[4], pfr;
#pragma unroll
        for (int dt = 0; dt < 4; ++dt)
          vf[dt] = *(const bf16x8*)(Vs + (dt * 16 + lr) * 64 + (((kx * 4 + quad) ^ e7) * 8));
        pfr = *(const bf16x8*)(Ps + (wave * 16 + lr) * 64 + (((kx * 4 + quad) ^ e7) * 8));
        __builtin_amdgcn_s_setprio(1);
#pragma unroll
        for (int dt = 0; dt < 4; ++dt)
          acc[dt] = __builtin_amdgcn_mfma_f32_16x16x32_bf16(vf[dt], pfr, acc[dt], 0, 0, 0);
        __builtin_amdgcn_s_setprio(0);
      }

      // ---- all waves done READING tile kt; prefetch loads stay in flight
      __builtin_amdgcn_s_barrier();
      __builtin_amdgcn_sched_barrier(0);
      if (pf) {
        // compiler inserts s_waitcnt vmcnt(0) before first use of sk*/sv*
        *(bf16x8*)(Ks + srow * 64 + su) = sk0;
        *(bf16x8*)(Ks + (srow + 32) * 64 + su) = sk1;
        *(bf16x8*)(Vs + srow * 64 + su) = sv0;
        *(bf16x8*)(Vs + (srow + 32) * 64 + su) = sv1;
        asm volatile("s_waitcnt lgkmcnt(0)" ::: "memory");
      }
      __builtin_amdgcn_s_barrier();  // tile kt+1 visible to all waves
      __builtin_amdgcn_sched_barrier(0);
    }

    // Epilogue: y = O / l — lane owns q-row lr, d = dt*16+quad*4+r
    float inv = 1.0f / l_i;
    int qrow = qrow0 + lr;
#pragma unroll
    for (int dt = 0; dt < 4; ++dt) {
      bf16x4 ov;
#pragma unroll
      for (int r = 0; r < 4; ++r) ov[r] = (bf16)(acc[dt][r] * inv);
      *(bf16x4*)(q + ((size_t)(b * N_ + qrow) * H_ + h) * D_ + dt * 16 + quad * 4) = ov;
    }
  }
}

// ---------------------------------------------------------------------------
extern "C" void kernel_launch(void* const* d_in, const int* in_sizes, int n_in,
                              void* d_out, int out_size, void* d_ws, size_t ws_size,
                              hipStream_t stream) {
  // Inputs FP32; output FP32. Intermediates bf16.
  const float* x = (const float*)d_in[0];
  const float* wq = (const float*)d_in[1];
  const float* wk = (const float*)d_in[2];
  const float* wv = (const float*)d_in[3];
  const float* wo = (const float*)d_in[4];
  float* out = (float*)d_out;
  char* ws = (char*)d_ws;
  // ws (28 MB): q/y 16 MB [0,16M) | kv 8 MB [16M,24M) | region [24M,28M) is
  // time-shared: wqkvT (3 MB) -> vt (4 MB) -> woT (2 MB).
  bf16* q = (bf16*)(ws);
  bf16* kv = (bf16*)(ws + 16777216);
  bf16* vt = (bf16*)(ws + 25165824);
  bf16* wqkvT = (bf16*)(ws + 25165824);
  bf16* woT = (bf16*)(ws + 25165824);

  prep_qkv<<<dim3(384), 256, 0, stream>>>(wq, wk, wv, wqkvT);
  gemm_qkv<<<dim3(64, 12), 256, 0, stream>>>(x, wqkvT, q, kv);
  norm_rope<<<dim3(5120), 256, 0, stream>>>(q, kv);
  transpose_v<<<dim3(32, 16), 256, 0, stream>>>(kv, vt);
  attn<<<dim3(1536), 256, 0, stream>>>(q, kv, vt);
  prep_wo<<<dim3(256), 256, 0, stream>>>(wo, woT);
  gemm_out<<<dim3(64, 8), 256, 0, stream>>>(q, woT, out);
}

// Round 9
// 247.109 us; speedup vs baseline: 2.3933x; 1.0430x over previous
//
#include <hip/hip_runtime.h>

typedef __bf16 bf16;
typedef __bf16 bf16x8 __attribute__((ext_vector_type(8)));
typedef __bf16 bf16x4 __attribute__((ext_vector_type(4)));
typedef float f32x4 __attribute__((ext_vector_type(4)));

#define B_ 4
#define N_ 2048
#define C_ 1024
#define H_ 16
#define HKV_ 4
#define D_ 64

// fold: 1.5 (qk_gain) * 0.125 (1/sqrt(64)) * log2(e)  -> use exp2f in softmax
#define QSCALE 0.2705053201666806f
#define NEGINF (-1.0e30f)

// ---------------------------------------------------------------------------
// Weight prep: w [1024 k][ncols n] f32 -> wT [n][1024 k] bf16 (+ convert).
__global__ __launch_bounds__(256) void prep_qkv(const float* __restrict__ wq,
                                                const float* __restrict__ wk,
                                                const float* __restrict__ wv,
                                                bf16* __restrict__ wT) {
  __shared__ __align__(16) bf16 lds[64 * 72];
  int bx = blockIdx.x;
  const float* w;
  int ncols, tk, tn, nbase;
  if (bx < 256) {
    w = wq; ncols = 1024; tk = bx >> 4; tn = bx & 15; nbase = 0;
  } else if (bx < 320) {
    int t = bx - 256;
    w = wk; ncols = 256; tk = t >> 2; tn = t & 3; nbase = 1024;
  } else {
    int t = bx - 320;
    w = wv; ncols = 256; tk = t >> 2; tn = t & 3; nbase = 1280;
  }
  int tid = threadIdx.x;
#pragma unroll
  for (int i = 0; i < 4; ++i) {
    int c = tid + i * 256;
    int kr = c >> 4, n4 = (c & 15) * 4;
    f32x4 v = *(const f32x4*)(w + (size_t)(tk * 64 + kr) * ncols + tn * 64 + n4);
    bf16x4 b;
#pragma unroll
    for (int j = 0; j < 4; ++j) b[j] = (bf16)v[j];
    *(bf16x4*)(lds + kr * 72 + n4) = b;
  }
  __syncthreads();
#pragma unroll
  for (int i = 0; i < 2; ++i) {
    int c = tid + i * 256;
    int n = c >> 3, koff = (c & 7) * 8;
    bf16x8 tv;
#pragma unroll
    for (int j = 0; j < 8; ++j) tv[j] = lds[(koff + j) * 72 + n];
    *(bf16x8*)(wT + (size_t)(nbase + tn * 64 + n) * 1024 + tk * 64 + koff) = tv;
  }
}

// Single-matrix variant for wo (1024x1024), launched after attn (aliases vt).
__global__ __launch_bounds__(256) void prep_wo(const float* __restrict__ w,
                                               bf16* __restrict__ wT) {
  __shared__ __align__(16) bf16 lds[64 * 72];
  int tk = blockIdx.x >> 4, tn = blockIdx.x & 15;
  int tid = threadIdx.x;
#pragma unroll
  for (int i = 0; i < 4; ++i) {
    int c = tid + i * 256;
    int kr = c >> 4, n4 = (c & 15) * 4;
    f32x4 v = *(const f32x4*)(w + (size_t)(tk * 64 + kr) * 1024 + tn * 64 + n4);
    bf16x4 b;
#pragma unroll
    for (int j = 0; j < 4; ++j) b[j] = (bf16)v[j];
    *(bf16x4*)(lds + kr * 72 + n4) = b;
  }
  __syncthreads();
#pragma unroll
  for (int i = 0; i < 2; ++i) {
    int c = tid + i * 256;
    int n = c >> 3, koff = (c & 7) * 8;
    bf16x8 tv;
#pragma unroll
    for (int j = 0; j < 8; ++j) tv[j] = lds[(koff + j) * 72 + n];
    *(bf16x8*)(wT + (size_t)(tn * 64 + n) * 1024 + tk * 64 + koff) = tv;
  }
}

// ---------------------------------------------------------------------------
// Fused QKV projection, bf16 pre-transposed weights. Grid (64, 12).
// Attn-style async staging: next k-tile's global loads are issued into
// registers BEFORE the MFMA section; LDS writes after a raw s_barrier.
__global__ __launch_bounds__(256) void gemm_qkv(const float* __restrict__ x,
                                                const bf16* __restrict__ wT,
                                                bf16* __restrict__ qb,
                                                bf16* __restrict__ kvb) {
  __shared__ __align__(16) bf16 As[128 * 72];
  __shared__ __align__(16) bf16 Bs[128 * 72];
  int by = blockIdx.y;
  int n0 = by * 128;  // row into wT[1536][1024]
  bf16* Out;
  int ostride, ocol0;
  if (by < 8) {
    Out = qb; ostride = 1024; ocol0 = by * 128;
  } else if (by < 10) {
    Out = kvb; ostride = 512; ocol0 = (by - 8) * 128;
  } else {
    Out = kvb; ostride = 512; ocol0 = 256 + (by - 10) * 128;
  }
  int m0 = blockIdx.x * 128;
  int tid = threadIdx.x;
  int wave = tid >> 6, lane = tid & 63;
  int quad = lane >> 4, lr = lane & 15;
  int wr = (wave >> 1) * 64, wc = (wave & 1) * 64;
  int arow = tid >> 4, aoff = (tid & 15) * 4;  // A staging coords (+16 rows x8)
  int brow = tid >> 3, boff = (tid & 7) * 8;   // B staging coords (+32 rows x4)

  f32x4 acc[4][4];
  const f32x4 z = {0.f, 0.f, 0.f, 0.f};
#pragma unroll
  for (int i = 0; i < 4; ++i)
#pragma unroll
    for (int j = 0; j < 4; ++j) acc[i][j] = z;

  f32x4 sa[8];
  bf16x8 sb[4];
  // ---- prologue: stage k0 = 0
#pragma unroll
  for (int i = 0; i < 8; ++i)
    sa[i] = *(const f32x4*)(x + (size_t)(m0 + arow + i * 16) * 1024 + aoff);
#pragma unroll
  for (int i = 0; i < 4; ++i)
    sb[i] = *(const bf16x8*)(wT + (size_t)(n0 + brow + i * 32) * 1024 + boff);
#pragma unroll
  for (int i = 0; i < 8; ++i) {
    bf16x4 a16;
#pragma unroll
    for (int j = 0; j < 4; ++j) a16[j] = (bf16)sa[i][j];
    *(bf16x4*)(As + (arow + i * 16) * 72 + aoff) = a16;
  }
#pragma unroll
  for (int i = 0; i < 4; ++i) *(bf16x8*)(Bs + (brow + i * 32) * 72 + boff) = sb[i];
  asm volatile("s_waitcnt lgkmcnt(0)" ::: "memory");
  __builtin_amdgcn_s_barrier();
  __builtin_amdgcn_sched_barrier(0);

  for (int k0 = 0; k0 < 1024; k0 += 64) {
    bool pf = (k0 + 64 < 1024);
    if (pf) {
#pragma unroll
      for (int i = 0; i < 8; ++i)
        sa[i] = *(const f32x4*)(x + (size_t)(m0 + arow + i * 16) * 1024 + k0 + 64 + aoff);
#pragma unroll
      for (int i = 0; i < 4; ++i)
        sb[i] = *(const bf16x8*)(wT + (size_t)(n0 + brow + i * 32) * 1024 + k0 + 64 + boff);
    }
#pragma unroll
    for (int kx = 0; kx < 2; ++kx) {
      bf16x8 af[4], bfr[4];
#pragma unroll
      for (int t = 0; t < 4; ++t) {
        af[t] = *(const bf16x8*)(As + (wr + t * 16 + lr) * 72 + kx * 32 + quad * 8);
        bfr[t] = *(const bf16x8*)(Bs + (wc + t * 16 + lr) * 72 + kx * 32 + quad * 8);
      }
      __builtin_amdgcn_s_setprio(1);
#pragma unroll
      for (int rt = 0; rt < 4; ++rt)
#pragma unroll
        for (int ct = 0; ct < 4; ++ct)
          acc[rt][ct] = __builtin_amdgcn_mfma_f32_16x16x32_bf16(af[rt], bfr[ct],
                                                                acc[rt][ct], 0, 0, 0);
      __builtin_amdgcn_s_setprio(0);
    }
    // all waves consumed As/Bs for tile k0 (ds_reads drained before MFMAs)
    __builtin_amdgcn_s_barrier();
    __builtin_amdgcn_sched_barrier(0);
    if (pf) {
      // compiler inserts s_waitcnt vmcnt as sa/sb are first used here
#pragma unroll
      for (int i = 0; i < 8; ++i) {
        bf16x4 a16;
#pragma unroll
        for (int j = 0; j < 4; ++j) a16[j] = (bf16)sa[i][j];
        *(bf16x4*)(As + (arow + i * 16) * 72 + aoff) = a16;
      }
#pragma unroll
      for (int i = 0; i < 4; ++i) *(bf16x8*)(Bs + (brow + i * 32) * 72 + boff) = sb[i];
      asm volatile("s_waitcnt lgkmcnt(0)" ::: "memory");
    }
    __builtin_amdgcn_s_barrier();
    __builtin_amdgcn_sched_barrier(0);
  }
#pragma unroll
  for (int rt = 0; rt < 4; ++rt)
#pragma unroll
    for (int ct = 0; ct < 4; ++ct)
#pragma unroll
      for (int r = 0; r < 4; ++r) {
        int row = m0 + wr + rt * 16 + quad * 4 + r;
        int col = ocol0 + wc + ct * 16 + lr;
        Out[(size_t)row * ostride + col] = (bf16)acc[rt][ct][r];
      }
}

// ---------------------------------------------------------------------------
// Output projection: A = attn output (bf16), B^T = woT bf16, C = float out.
// Same async-staging structure (both operands bf16).
__global__ __launch_bounds__(256) void gemm_out(const bf16* __restrict__ A,
                                                const bf16* __restrict__ Bt,
                                                float* __restrict__ C) {
  __shared__ __align__(16) bf16 As[128 * 72];
  __shared__ __align__(16) bf16 Bs[128 * 72];
  int m0 = blockIdx.x * 128, n0 = blockIdx.y * 128;
  int tid = threadIdx.x;
  int wave = tid >> 6, lane = tid & 63;
  int quad = lane >> 4, lr = lane & 15;
  int wr = (wave >> 1) * 64, wc = (wave & 1) * 64;
  int brow = tid >> 3, boff = (tid & 7) * 8;

  f32x4 acc[4][4];
  const f32x4 z = {0.f, 0.f, 0.f, 0.f};
#pragma unroll
  for (int i = 0; i < 4; ++i)
#pragma unroll
    for (int j = 0; j < 4; ++j) acc[i][j] = z;

  bf16x8 sa[4], sb[4];
#pragma unroll
  for (int i = 0; i < 4; ++i) {
    sa[i] = *(const bf16x8*)(A + (size_t)(m0 + brow + i * 32) * 1024 + boff);
    sb[i] = *(const bf16x8*)(Bt + (size_t)(n0 + brow + i * 32) * 1024 + boff);
  }
#pragma unroll
  for (int i = 0; i < 4; ++i) {
    *(bf16x8*)(As + (brow + i * 32) * 72 + boff) = sa[i];
    *(bf16x8*)(Bs + (brow + i * 32) * 72 + boff) = sb[i];
  }
  asm volatile("s_waitcnt lgkmcnt(0)" ::: "memory");
  __builtin_amdgcn_s_barrier();
  __builtin_amdgcn_sched_barrier(0);

  for (int k0 = 0; k0 < 1024; k0 += 64) {
    bool pf = (k0 + 64 < 1024);
    if (pf) {
#pragma unroll
      for (int i = 0; i < 4; ++i) {
        sa[i] = *(const bf16x8*)(A + (size_t)(m0 + brow + i * 32) * 1024 + k0 + 64 + boff);
        sb[i] = *(const bf16x8*)(Bt + (size_t)(n0 + brow + i * 32) * 1024 + k0 + 64 + boff);
      }
    }
#pragma unroll
    for (int kx = 0; kx < 2; ++kx) {
      bf16x8 af[4], bfr[4];
#pragma unroll
      for (int t = 0; t < 4; ++t) {
        af[t] = *(const bf16x8*)(As + (wr + t * 16 + lr) * 72 + kx * 32 + quad * 8);
        bfr[t] = *(const bf16x8*)(Bs + (wc + t * 16 + lr) * 72 + kx * 32 + quad * 8);
      }
      __builtin_amdgcn_s_setprio(1);
#pragma unroll
      for (int rt = 0; rt < 4; ++rt)
#pragma unroll
        for (int ct = 0; ct < 4; ++ct)
          acc[rt][ct] = __builtin_amdgcn_mfma_f32_16x16x32_bf16(af[rt], bfr[ct],
                                                                acc[rt][ct], 0, 0, 0);
      __builtin_amdgcn_s_setprio(0);
    }
    __builtin_amdgcn_s_barrier();
    __builtin_amdgcn_sched_barrier(0);
    if (pf) {
#pragma unroll
      for (int i = 0; i < 4; ++i) {
        *(bf16x8*)(As + (brow + i * 32) * 72 + boff) = sa[i];
        *(bf16x8*)(Bs + (brow + i * 32) * 72 + boff) = sb[i];
      }
      asm volatile("s_waitcnt lgkmcnt(0)" ::: "memory");
    }
    __builtin_amdgcn_s_barrier();
    __builtin_amdgcn_sched_barrier(0);
  }
#pragma unroll
  for (int rt = 0; rt < 4; ++rt)
#pragma unroll
    for (int ct = 0; ct < 4; ++ct)
#pragma unroll
      for (int r = 0; r < 4; ++r) {
        int row = m0 + wr + rt * 16 + quad * 4 + r;
        int col = n0 + wc + ct * 16 + lr;
        C[(size_t)row * 1024 + col] = acc[rt][ct][r];
      }
}

// ---------------------------------------------------------------------------
// V transpose: kv [B*N][512] -> vt [B][HKV][D][N].
__global__ __launch_bounds__(256) void transpose_v(const bf16* __restrict__ kv,
                                                   bf16* __restrict__ vt) {
  __shared__ __align__(16) bf16 lds[64 * 72];
  int nt = blockIdx.x;
  int bh = blockIdx.y;
  int b = bh >> 2, hkv = bh & 3;
  int tid = threadIdx.x;
#pragma unroll
  for (int i = 0; i < 2; ++i) {
    int c = tid + i * 256;
    int tok = c >> 3, off = (c & 7) * 8;
    *(bf16x8*)(lds + tok * 72 + off) =
        *(const bf16x8*)(kv + (size_t)(b * N_ + nt * 64 + tok) * 512 + 256 + hkv * 64 + off);
  }
  __syncthreads();
#pragma unroll
  for (int i = 0; i < 2; ++i) {
    int c = tid + i * 256;
    int d = c >> 3, toff = (c & 7) * 8;
    bf16x8 tv;
#pragma unroll
    for (int j = 0; j < 8; ++j) tv[j] = lds[(toff + j) * 72 + d];
    *(bf16x8*)(vt + ((size_t)bh * 64 + d) * N_ + nt * 64 + toff) = tv;
  }
}

// ---------------------------------------------------------------------------
// Per-head RMSNorm + RoPE, in place — VECTORIZED (G13): 8 lanes per head,
// bf16x8 per lane (16 B). RMS reduce = 3 shfls in the octet; RoPE partner
// d+-32 = shfl_xor(xn, 4); sign = -(e<4). Grid 5120 x 256 (32 heads/block).
__global__ __launch_bounds__(256) void norm_rope(bf16* __restrict__ q,
                                                 bf16* __restrict__ kv) {
  int tid = threadIdx.x;
  int g = (blockIdx.x << 5) + (tid >> 3);  // global head id, 163840 total
  int e = tid & 7;                          // octet index within head
  int t = g / 20;
  int sub = g - t * 20;
  int n = t & (N_ - 1);
  bf16* ptr;
  float oscale;
  if (sub < 16) {
    ptr = q + (size_t)t * 1024 + sub * 64;
    oscale = QSCALE;
  } else {
    ptr = kv + (size_t)t * 512 + (sub - 16) * 64;
    oscale = 1.0f;
  }
  bf16x8 v = *(const bf16x8*)(ptr + e * 8);
  float xv[8];
  float ss = 0.f;
#pragma unroll
  for (int i = 0; i < 8; ++i) {
    xv[i] = (float)v[i];
    ss += xv[i] * xv[i];
  }
  ss += __shfl_xor(ss, 1);
  ss += __shfl_xor(ss, 2);
  ss += __shfl_xor(ss, 4);
  float rn = rsqrtf(ss * (1.0f / 64.0f) + 1.1920929e-07f);
  float base = (float)((e & 3) * 8);  // d mod 32 base for this octet
  bf16x8 o;
#pragma unroll
  for (int i = 0; i < 8; ++i) {
    float xn = xv[i] * rn;
    float pr = __shfl_xor(xn, 4);  // partner element d +- 32 (rn is head-uniform)
    float rot = (e < 4) ? -pr : pr;
    float ang = (float)n * exp2f(-0.41524101186092029f * (base + (float)i));
    float sv, cv;
    __sincosf(ang, &sv, &cv);
    o[i] = (bf16)((xn * cv + rot * sv) * oscale);
  }
  *(bf16x8*)(ptr + e * 8) = o;
}

// ---------------------------------------------------------------------------
// Causal flash attention with GQA — TRANSPOSED dataflow (S^T / O^T),
// XOR-swizzled LDS, no-shift softmax.
// Round-8: COMPLEMENT-PAIR static schedule + XCD swizzle.
//   Item = q-tile pair {j, 31-j}: cost (j+1)+(32-j) = 33 k-tile-units for
//   EVERY item -> 1024 uniform blocks, 4/CU, all finish together. Replaces
//   the 2048-item queue whose 32x item-cost spread left a long decay tail
//   (37% time-avg occupancy). Queue/atomic machinery deleted.
//   XCD swizzle: bid -> orig = (bid&7)*128 + bid>>3; group = orig>>6 is
//   (b,hkv) -> all 64 blocks sharing K/V land on one XCD; K+V = 512 KB per
//   group, 2 groups per 4 MB XCD-L2 -> K/V streams from L2, not HBM.
__global__ __launch_bounds__(256) void attn(bf16* __restrict__ q,
                                            const bf16* __restrict__ kv,
                                            const bf16* __restrict__ vt) {
  __shared__ __align__(16) bf16 Ks[64 * 64];  // [key][d], swizzled
  __shared__ __align__(16) bf16 Vs[64 * 64];  // [d][key], swizzled
  __shared__ __align__(16) bf16 Ps[64 * 64];  // [q-row][key], swizzled
  int bid = blockIdx.x;
  int orig = (bid & 7) * 128 + (bid >> 3);  // bijective (1024 % 8 == 0)
  int grp = orig >> 6;                      // (b,hkv) group, 0..15
  int inner = orig & 63;
  int b = grp >> 2, hkv = grp & 3;
  int h = hkv * 4 + (inner & 3);
  int p = inner >> 2;                       // pair index, 0..15
  int tid = threadIdx.x;
  int wave = tid >> 6, lane = tid & 63;
  int quad = lane >> 4, lr = lane & 15;
  int srow = tid >> 3, soff = (tid & 7) * 8;
  int su = ((tid & 7) ^ (srow & 7)) * 8;  // swizzled LDS unit (same for srow+32)
  int e7 = lr & 7;                        // read-side row XOR key
  const f32x4 z = {0.f, 0.f, 0.f, 0.f};

#pragma unroll 1
  for (int s = 0; s < 2; ++s) {
    int j = s ? (31 - p) : p;  // q-tile index; costs sum to 33 units
    __syncthreads();           // all waves done with previous sub-item's LDS
    int qrow0 = j * 64 + wave * 16;  // this wave's first q-row
    int nkt = j + 1;

    // Q fragments (B-operand = Q^T): lane holds Q[qrow0+lr][kx*32+quad*8..]
    bf16x8 qf[2];
#pragma unroll
    for (int kx = 0; kx < 2; ++kx)
      qf[kx] = *(const bf16x8*)(
          q + ((size_t)(b * N_ + qrow0 + lr) * H_ + h) * D_ + kx * 32 + quad * 8);

    f32x4 acc[4];  // acc[dt] = O^T tile: row d=dt*16+quad*4+r, col qrow=lr
    float l_i = 0.f;
#pragma unroll
    for (int dt = 0; dt < 4; ++dt) acc[dt] = z;

    // staging pointers (strength-reduced; advance per tile)
    const bf16* kp = kv + (size_t)(b * N_ + srow) * 512 + hkv * 64 + soff;
    const bf16* vp = vt + ((size_t)(b * HKV_ + hkv) * 64 + srow) * N_ + soff;

    // ---- prologue: stage tile 0 synchronously
    bf16x8 sk0, sk1, sv0, sv1;
    sk0 = *(const bf16x8*)(kp);
    sk1 = *(const bf16x8*)(kp + 32 * 512);
    sv0 = *(const bf16x8*)(vp);
    sv1 = *(const bf16x8*)(vp + 32 * N_);
    *(bf16x8*)(Ks + srow * 64 + su) = sk0;
    *(bf16x8*)(Ks + (srow + 32) * 64 + su) = sk1;
    *(bf16x8*)(Vs + srow * 64 + su) = sv0;
    *(bf16x8*)(Vs + (srow + 32) * 64 + su) = sv1;
    asm volatile("s_waitcnt lgkmcnt(0)" ::: "memory");
    __builtin_amdgcn_s_barrier();
    __builtin_amdgcn_sched_barrier(0);

    for (int kt = 0; kt < nkt; ++kt) {
      // ---- issue NEXT tile's global loads early (in flight across compute)
      bool pf = (kt + 1 < nkt);
      if (pf) {
        kp += 64 * 512;
        vp += 64;
        sk0 = *(const bf16x8*)(kp);
        sk1 = *(const bf16x8*)(kp + 32 * 512);
        sv0 = *(const bf16x8*)(vp);
        sv1 = *(const bf16x8*)(vp + 32 * N_);
      }

      // S^T = K·Q^T: st[ct] — key = kt*64 + ct*16 + quad*4 + r, qrow col = lr
      f32x4 st[4];
#pragma unroll
      for (int ct = 0; ct < 4; ++ct) st[ct] = z;
#pragma unroll
      for (int kx = 0; kx < 2; ++kx) {
        bf16x8 kf[4];
#pragma unroll
        for (int ct = 0; ct < 4; ++ct)
          kf[ct] = *(const bf16x8*)(Ks + (ct * 16 + lr) * 64 + (((kx * 4 + quad) ^ e7) * 8));
        __builtin_amdgcn_s_setprio(1);
#pragma unroll
        for (int ct = 0; ct < 4; ++ct)
          st[ct] = __builtin_amdgcn_mfma_f32_16x16x32_bf16(kf[ct], qf[kx], st[ct], 0, 0, 0);
        __builtin_amdgcn_s_setprio(0);
      }
      // Causal mask — only the diagonal tile kt == j crosses the diagonal
      if (kt == j) {
        int qrow = qrow0 + lr;
#pragma unroll
        for (int ct = 0; ct < 4; ++ct)
#pragma unroll
          for (int r = 0; r < 4; ++r) {
            int key = kt * 64 + ct * 16 + quad * 4 + r;
            if (key > qrow) st[ct][r] = NEGINF;
          }
      }
      // No-shift softmax: p = exp2(s) directly (|s| <= 17.32 by RMS bound);
      // masked entries exp2(-1e30) = 0. l accumulates unnormalized.
      float rs = 0.f;
#pragma unroll
      for (int ct = 0; ct < 4; ++ct)
#pragma unroll
        for (int r = 0; r < 4; ++r) {
          float pv = exp2f(st[ct][r]);
          st[ct][r] = pv;
          rs += pv;
        }
      rs += __shfl_xor(rs, 16);
      rs += __shfl_xor(rs, 32);
      l_i += rs;
      // P^T -> Ps[qrow][key] (swizzled): b64 writes, keys quad*4+r contiguous
#pragma unroll
      for (int ct = 0; ct < 4; ++ct) {
        bf16x4 pk;
#pragma unroll
        for (int r = 0; r < 4; ++r) pk[r] = (bf16)st[ct][r];
        int pu = (((ct * 2) + (quad >> 1)) ^ e7) * 8 + (quad & 1) * 4;
        *(bf16x4*)(Ps + (wave * 16 + lr) * 64 + pu) = pk;
      }
      // Wave-local LDS ordering (rows wave-private, guard wave-uniform)
      asm volatile("s_waitcnt lgkmcnt(0)" ::: "memory");
      // O^T += V^T·P^T
#pragma unroll
      for (int kx = 0; kx < 2; ++kx) {
        bf16x8 vf[4], pfr;
#pragma unroll
        for (int dt = 0; dt < 4; ++dt)
          vf[dt] = *(const bf16x8*)(Vs + (dt * 16 + lr) * 64 + (((kx * 4 + quad) ^ e7) * 8));
        pfr = *(const bf16x8*)(Ps + (wave * 16 + lr) * 64 + (((kx * 4 + quad) ^ e7) * 8));
        __builtin_amdgcn_s_setprio(1);
#pragma unroll
        for (int dt = 0; dt < 4; ++dt)
          acc[dt] = __builtin_amdgcn_mfma_f32_16x16x32_bf16(vf[dt], pfr, acc[dt], 0, 0, 0);
        __builtin_amdgcn_s_setprio(0);
      }

      // ---- all waves done READING tile kt; prefetch loads stay in flight
      __builtin_amdgcn_s_barrier();
      __builtin_amdgcn_sched_barrier(0);
      if (pf) {
        // compiler inserts s_waitcnt vmcnt(0) before first use of sk*/sv*
        *(bf16x8*)(Ks + srow * 64 + su) = sk0;
        *(bf16x8*)(Ks + (srow + 32) * 64 + su) = sk1;
        *(bf16x8*)(Vs + srow * 64 + su) = sv0;
        *(bf16x8*)(Vs + (srow + 32) * 64 + su) = sv1;
        asm volatile("s_waitcnt lgkmcnt(0)" ::: "memory");
      }
      __builtin_amdgcn_s_barrier();  // tile kt+1 visible to all waves
      __builtin_amdgcn_sched_barrier(0);
    }

    // Epilogue: y = O / l — lane owns q-row lr, d = dt*16+quad*4+r
    float inv = 1.0f / l_i;
    int qrow = qrow0 + lr;
#pragma unroll
    for (int dt = 0; dt < 4; ++dt) {
      bf16x4 ov;
#pragma unroll
      for (int r = 0; r < 4; ++r) ov[r] = (bf16)(acc[dt][r] * inv);
      *(bf16x4*)(q + ((size_t)(b * N_ + qrow) * H_ + h) * D_ + dt * 16 + quad * 4) = ov;
    }
  }
}

// ---------------------------------------------------------------------------
extern "C" void kernel_launch(void* const* d_in, const int* in_sizes, int n_in,
                              void* d_out, int out_size, void* d_ws, size_t ws_size,
                              hipStream_t stream) {
  // Inputs FP32; output FP32. Intermediates bf16.
  const float* x = (const float*)d_in[0];
  const float* wq = (const float*)d_in[1];
  const float* wk = (const float*)d_in[2];
  const float* wv = (const float*)d_in[3];
  const float* wo = (const float*)d_in[4];
  float* out = (float*)d_out;
  char* ws = (char*)d_ws;
  // ws (28 MB): q/y 16 MB [0,16M) | kv 8 MB [16M,24M) | region [24M,28M) is
  // time-shared: wqkvT (3 MB) -> vt (4 MB) -> woT (2 MB).
  bf16* q = (bf16*)(ws);
  bf16* kv = (bf16*)(ws + 16777216);
  bf16* vt = (bf16*)(ws + 25165824);
  bf16* wqkvT = (bf16*)(ws + 25165824);
  bf16* woT = (bf16*)(ws + 25165824);

  prep_qkv<<<dim3(384), 256, 0, stream>>>(wq, wk, wv, wqkvT);
  gemm_qkv<<<dim3(64, 12), 256, 0, stream>>>(x, wqkvT, q, kv);
  norm_rope<<<dim3(5120), 256, 0, stream>>>(q, kv);
  transpose_v<<<dim3(32, 16), 256, 0, stream>>>(kv, vt);
  attn<<<dim3(1024), 256, 0, stream>>>(q, kv, vt);
  prep_wo<<<dim3(256), 256, 0, stream>>>(wo, woT);
  gemm_out<<<dim3(64, 8), 256, 0, stream>>>(q, woT, out);
}